// Round 10
// baseline (554.893 us; speedup 1.0000x reference)
//
#include <hip/hip_runtime.h>
#include <hip/hip_bf16.h>

#define SLOW 32
#define MSG 16
#define TSTEPS 4
#define BATCH 8
#define NI0 256
#define NO0 128
#define NI1 128
#define NO1 64

typedef __bf16 bf16x8 __attribute__((ext_vector_type(8)));
typedef float f32x4 __attribute__((ext_vector_type(4)));

__device__ __forceinline__ float rcpf(float x) { return __builtin_amdgcn_rcpf(x); }
__device__ __forceinline__ float sigf(float x) { return rcpf(1.f + __expf(-x)); }
__device__ __forceinline__ float tanh_apx(float x) {
    float xc = fminf(fmaxf(x, -15.f), 15.f);
    float e = __expf(-2.f * xc);
    return (1.f - e) * rcpf(1.f + e);
}
__device__ __forceinline__ unsigned short f2bf(float x) {
    __bf16 h = (__bf16)x;
    return __builtin_bit_cast(unsigned short, h);
}
__device__ __forceinline__ float bf2f(unsigned short u) {
    __bf16 h = __builtin_bit_cast(__bf16, u);
    return (float)h;
}
__device__ __forceinline__ float sum16(float v) {
    v += __shfl_xor(v, 1); v += __shfl_xor(v, 2);
    v += __shfl_xor(v, 4); v += __shfl_xor(v, 8);
    return v;
}

// ---------------------------------------------------------------------------
// k_prep: pack B-fragments (bf16) for Wh (8 n-tiles), Wf, Wb.
// frag slot (lane l, elem e) = W[k = (l>>4)*8 + e][col = nt*16 + (l&15)]
// ---------------------------------------------------------------------------
__global__ void k_prep(const float* __restrict__ Wh, const float* __restrict__ Wf,
                       const float* __restrict__ Wb,
                       unsigned short* __restrict__ WhBp,
                       unsigned short* __restrict__ WfBp,
                       unsigned short* __restrict__ WbBp) {
    int i = blockIdx.x * 256 + threadIdx.x;
    if (i < 4096) {
        int e = i & 7, l = (i >> 3) & 63, nt = i >> 9;
        int k = (l >> 4) * 8 + e, col = nt * 16 + (l & 15);
        WhBp[i] = f2bf(Wh[k * 128 + col]);
    } else if (i < 4608) {
        int j = i - 4096;
        int e = j & 7, l = j >> 3;
        int k = (l >> 4) * 8 + e;
        WfBp[j] = f2bf(Wf[k * 16 + (l & 15)]);
    } else if (i < 5120) {
        int j = i - 4608;
        int e = j & 7, l = j >> 3;
        int k = (l >> 4) * 8 + e;
        WbBp[j] = f2bf(Wb[k * 16 + (l & 15)]);
    }
}

// ---------------------------------------------------------------------------
// merge: mean over batch for slow channels s<16.
// layouts: h bf16 [b][no][cell][32], c f32 [b][no][cell][32]
// ---------------------------------------------------------------------------
__global__ void k_merge(unsigned int* __restrict__ h0, float* __restrict__ c0,
                        unsigned int* __restrict__ h1, float* __restrict__ c1) {
    int idx = blockIdx.x * 256 + threadIdx.x;
    if (idx < 262144) {  // l0 h
        int u = idx & 7, cell = (idx >> 3) & 255, no = idx >> 11;
        size_t base = ((size_t)no * 256 + cell) * 16 + u;
        const size_t strd = (size_t)128 * 256 * 16;
        float s0 = 0.f, s1 = 0.f;
#pragma unroll
        for (int b = 0; b < 8; b++) {
            unsigned int v = h0[base + b * strd];
            s0 += bf2f((unsigned short)(v & 0xffff));
            s1 += bf2f((unsigned short)(v >> 16));
        }
        unsigned int mv = (unsigned int)f2bf(s0 * 0.125f) |
                          ((unsigned int)f2bf(s1 * 0.125f) << 16);
#pragma unroll
        for (int b = 0; b < 8; b++) h0[base + b * strd] = mv;
        return;
    }
    idx -= 262144;
    if (idx < 131072) {  // l0 c
        int s4 = idx & 3, cell = (idx >> 2) & 255, no = idx >> 10;
        float4* C = (float4*)c0;
        size_t base = ((size_t)no * 256 + cell) * 8 + s4;
        const size_t strd = (size_t)128 * 256 * 8;
        float4 a = {0.f, 0.f, 0.f, 0.f};
#pragma unroll
        for (int b = 0; b < 8; b++) {
            float4 v = C[base + b * strd];
            a.x += v.x; a.y += v.y; a.z += v.z; a.w += v.w;
        }
        a.x *= 0.125f; a.y *= 0.125f; a.z *= 0.125f; a.w *= 0.125f;
#pragma unroll
        for (int b = 0; b < 8; b++) C[base + b * strd] = a;
        return;
    }
    idx -= 131072;
    if (idx < 65536) {  // l1 h
        int u = idx & 7, cell = (idx >> 3) & 127, no = idx >> 10;
        size_t base = ((size_t)no * 128 + cell) * 16 + u;
        const size_t strd = (size_t)64 * 128 * 16;
        float s0 = 0.f, s1 = 0.f;
#pragma unroll
        for (int b = 0; b < 8; b++) {
            unsigned int v = h1[base + b * strd];
            s0 += bf2f((unsigned short)(v & 0xffff));
            s1 += bf2f((unsigned short)(v >> 16));
        }
        unsigned int mv = (unsigned int)f2bf(s0 * 0.125f) |
                          ((unsigned int)f2bf(s1 * 0.125f) << 16);
#pragma unroll
        for (int b = 0; b < 8; b++) h1[base + b * strd] = mv;
        return;
    }
    idx -= 65536;
    if (idx < 32768) {  // l1 c
        int s4 = idx & 3, cell = (idx >> 2) & 127, no = idx >> 9;
        float4* C = (float4*)c1;
        size_t base = ((size_t)no * 128 + cell) * 8 + s4;
        const size_t strd = (size_t)64 * 128 * 8;
        float4 a = {0.f, 0.f, 0.f, 0.f};
#pragma unroll
        for (int b = 0; b < 8; b++) {
            float4 v = C[base + b * strd];
            a.x += v.x; a.y += v.y; a.z += v.z; a.w += v.w;
        }
        a.x *= 0.125f; a.y *= 0.125f; a.z *= 0.125f; a.w *= 0.125f;
#pragma unroll
        for (int b = 0; b < 8; b++) C[base + b * strd] = a;
    }
}

// ---------------------------------------------------------------------------
// Layer 0 (MFMA, barrier-free recurrence): block = (b,no), 4 waves.
// Wave w owns m-tiles 4w..4w+3 (Hbf rows 64w..64w+63) — the h recurrence
// is wave-local, so NO __syncthreads in the micro loop. Barriers only
// after cooperative staging (BW/gsh) and before the cross-wave reduction.
// ---------------------------------------------------------------------------
__global__ __launch_bounds__(256, 4) void k_l0(
    const float* __restrict__ inp, const float* __restrict__ Wi,
    const unsigned short* __restrict__ WhBp, const float* __restrict__ b_lstm,
    const unsigned short* __restrict__ WfBp, const float* __restrict__ bf_,
    const float* __restrict__ ln_fs, const float* __restrict__ ln_fb,
    unsigned short* __restrict__ h0bf, float* __restrict__ c0g,
    const float* __restrict__ nb1, float* __restrict__ nfsum, int t) {
    int no = blockIdx.x & 127;
    int b = blockIdx.x >> 7;
    int tid = threadIdx.x;
    int w = __builtin_amdgcn_readfirstlane(tid >> 6);
    int l = tid & 63, lo = l & 15, hg = l >> 4;

    __shared__ unsigned short Hbf[256 * 40];
    __shared__ unsigned short BW[4096];
    __shared__ unsigned short BFr[512];
    __shared__ float gsh[128];
    __shared__ float mi_l[256];
    __shared__ float wi0[128];
    __shared__ float redn[4][16];

    {
        unsigned int* d = (unsigned int*)BW;
        const unsigned int* s = (const unsigned int*)WhBp;
#pragma unroll
        for (int i = tid; i < 2048; i += 256) d[i] = s[i];
        ((unsigned int*)BFr)[tid] = ((const unsigned int*)WfBp)[tid];
    }
    if (tid < 128) {
        float acc = b_lstm[tid];
        const float* nbr = nb1 + ((size_t)b * NO0 + no) * MSG;
#pragma unroll
        for (int m = 0; m < MSG; m++) acc += nbr[m] * Wi[(MSG + m) * 128 + tid];
        gsh[tid] = acc;
        wi0[tid] = Wi[tid];
    }
    mi_l[tid] = inp[((size_t)t * BATCH + b) * NI0 + tid];

    // stage H (bf16): thread = cell (wave-local rows)
    {
        const unsigned int* hsrc =
            (const unsigned int*)h0bf + ((size_t)(b * NO0 + no) * 256 + tid) * 16;
        unsigned int* hl = (unsigned int*)Hbf;
#pragma unroll
        for (int j = 0; j < 16; j++) hl[tid * 20 + j] = hsrc[j];
    }

    size_t cbase = (size_t)(b * NO0 + no) * 256 * 32;
    float cst[4][4][2];
#pragma unroll
    for (int mi_ = 0; mi_ < 4; mi_++)
#pragma unroll
        for (int r = 0; r < 4; r++) {
            int cell = (w * 4 + mi_) * 16 + hg * 4 + r;
#pragma unroll
            for (int hi = 0; hi < 2; hi++)
                cst[mi_][r][hi] = c0g[cbase + (size_t)cell * 32 + lo + 16 * hi];
        }
    __syncthreads();  // BW/gsh staged cooperatively — one barrier only

    float g8[8], w8[8];
#pragma unroll
    for (int nt = 0; nt < 8; nt++) { g8[nt] = gsh[lo + 16 * nt]; w8[nt] = wi0[lo + 16 * nt]; }
    f32x4 miv[4];
#pragma unroll
    for (int mi_ = 0; mi_ < 4; mi_++)
#pragma unroll
        for (int r = 0; r < 4; r++)
            miv[mi_][r] = mi_l[(w * 4 + mi_) * 16 + hg * 4 + r];

#pragma unroll
    for (int micro = 0; micro < 2; micro++) {
#pragma unroll
        for (int mi_ = 0; mi_ < 4; mi_++) {
            int mt = w * 4 + mi_;
            bf16x8 A = *(const bf16x8*)&Hbf[(mt * 16 + lo) * 40 + hg * 8];
            f32x4 acc[4];
#pragma unroll
            for (int g = 0; g < 4; g++) {
                int nt = 2 * g;
                bf16x8 B = *(const bf16x8*)&BW[(nt * 64 + l) * 8];
                f32x4 ci = g8[nt] + miv[mi_] * w8[nt];
                acc[g] = __builtin_amdgcn_mfma_f32_16x16x32_bf16(A, B, ci, 0, 0, 0);
            }
#pragma unroll
            for (int r = 0; r < 4; r++) {
                int cell = mt * 16 + hg * 4 + r;
                float cn = sigf(acc[1][r]) * cst[mi_][r][0] + sigf(acc[0][r]) * tanh_apx(acc[2][r]);
                cst[mi_][r][0] = cn;
                float hv = sigf(acc[3][r]) * tanh_apx(cn);
                unsigned short hb = f2bf(hv);
                Hbf[cell * 40 + lo] = hb;
                if (micro == 1) {
                    h0bf[cbase + (size_t)cell * 32 + lo] = hb;
                    c0g[cbase + (size_t)cell * 32 + lo] = cn;
                }
            }
#pragma unroll
            for (int g = 0; g < 4; g++) {
                int nt = 2 * g + 1;
                bf16x8 B = *(const bf16x8*)&BW[(nt * 64 + l) * 8];
                f32x4 ci = g8[nt] + miv[mi_] * w8[nt];
                acc[g] = __builtin_amdgcn_mfma_f32_16x16x32_bf16(A, B, ci, 0, 0, 0);
            }
#pragma unroll
            for (int r = 0; r < 4; r++) {
                int cell = mt * 16 + hg * 4 + r;
                float cn = sigf(acc[1][r]) * cst[mi_][r][1] + sigf(acc[0][r]) * tanh_apx(acc[2][r]);
                cst[mi_][r][1] = cn;
                float hv = sigf(acc[3][r]) * tanh_apx(cn);
                unsigned short hb = f2bf(hv);
                Hbf[cell * 40 + lo + 16] = hb;
                if (micro == 1) {
                    h0bf[cbase + (size_t)cell * 32 + lo + 16] = hb;
                    c0g[cbase + (size_t)cell * 32 + lo + 16] = cn;
                }
            }
        }
        // no barrier: recurrence is wave-local
    }

    // epilogue: fm = LN(h @ Wf + bf); nf raw sums (k_xf divides /256)
    bf16x8 Ff = *(const bf16x8*)&BFr[l * 8];
    float lnfs = ln_fs[lo], lnfb = ln_fb[lo];
    float bfv = bf_[lo];
    f32x4 cif = {bfv, bfv, bfv, bfv};
    float nfp = 0.f;
#pragma unroll
    for (int mi_ = 0; mi_ < 4; mi_++) {
        int mt = w * 4 + mi_;
        bf16x8 A = *(const bf16x8*)&Hbf[(mt * 16 + lo) * 40 + hg * 8];
        f32x4 f = __builtin_amdgcn_mfma_f32_16x16x32_bf16(A, Ff, cif, 0, 0, 0);
#pragma unroll
        for (int r = 0; r < 4; r++) {
            float x = f[r];
            float mean = sum16(x) * 0.0625f;
            float d = x - mean;
            float rs = rsqrtf(sum16(d * d) * 0.0625f + 1e-6f);
            nfp += d * rs * lnfs + lnfb;
        }
    }
    nfp += __shfl_xor(nfp, 16);
    nfp += __shfl_xor(nfp, 32);
    if (l < 16) redn[w][l] = nfp;
    __syncthreads();
    if (tid < 16)
        nfsum[((size_t)b * NO0 + no) * 16 + tid] =
            redn[0][tid] + redn[1][tid] + redn[2][tid] + redn[3][tid];
}

// ---------------------------------------------------------------------------
// k_xf: xf1T[b][gate][ni] = sum_m (nfsum[b][ni][m]/256) * Wi[m][gate]
// ---------------------------------------------------------------------------
__global__ __launch_bounds__(128) void k_xf(const float* __restrict__ nfsum,
                                            const float* __restrict__ Wi,
                                            float* __restrict__ xf1T) {
    int b = blockIdx.x >> 7;
    int k = blockIdx.x & 127;
    int no = threadIdx.x;
    const float* p = nfsum + ((size_t)b * NO0 + no) * MSG;
    float a = 0.f;
#pragma unroll
    for (int m = 0; m < MSG; m++) a += p[m] * Wi[m * 128 + k];
    xf1T[((size_t)b * 128 + k) * 128 + no] = a * (1.f / 256.f);
}

// ---------------------------------------------------------------------------
// Layer 1 (MFMA, split): block = (b,no1,q), 4 waves, 64 cells/block,
// wave w owns ONE m-tile (local rows 16w..16w+15). Barrier-free recurrence.
// Grid 1024 -> 4 blocks/CU resident.
// ---------------------------------------------------------------------------
__global__ __launch_bounds__(256, 4) void k_l1(
    const float* __restrict__ Wi, const unsigned short* __restrict__ WhBp,
    const float* __restrict__ b_lstm,
    const unsigned short* __restrict__ WfBp, const float* __restrict__ bf_,
    const float* __restrict__ ln_fs, const float* __restrict__ ln_fb,
    const unsigned short* __restrict__ WbBp, const float* __restrict__ bwb,
    const float* __restrict__ ln_bs, const float* __restrict__ ln_bb,
    unsigned short* __restrict__ h1bf, float* __restrict__ c1g,
    const float* __restrict__ xf1T, const float* __restrict__ gradP,
    const float* __restrict__ ohP,
    float* __restrict__ bm_g, float* __restrict__ outsum_part) {
    int q = blockIdx.x & 1;
    int no = (blockIdx.x >> 1) & 63;
    int b = blockIdx.x >> 7;
    int tid = threadIdx.x;
    int w = __builtin_amdgcn_readfirstlane(tid >> 6);
    int l = tid & 63, lo = l & 15, hg = l >> 4;

    __shared__ unsigned short Hbf[64 * 40];
    __shared__ unsigned short BW[4096];
    __shared__ unsigned short BFr[512];
    __shared__ unsigned short BBr[512];
    __shared__ float gsh[128];
    __shared__ float red[4];

    {
        unsigned int* d = (unsigned int*)BW;
        const unsigned int* s = (const unsigned int*)WhBp;
#pragma unroll
        for (int i = tid; i < 2048; i += 256) d[i] = s[i];
        ((unsigned int*)BFr)[tid] = ((const unsigned int*)WfBp)[tid];
        ((unsigned int*)BBr)[tid] = ((const unsigned int*)WbBp)[tid];
    }
    if (tid < 128) {
        float g = gradP[b * NO1 + no], oh = ohP[b * NO1 + no];
        gsh[tid] = b_lstm[tid] + g * Wi[MSG * 128 + tid] + oh * Wi[(MSG + 1) * 128 + tid];
    }

    // stage H: cell lc = tid>>2, 4 u32 each (wave-local rows)
    {
        int lc = tid >> 2, part = tid & 3;
        const unsigned int* hsrc =
            (const unsigned int*)h1bf +
            ((size_t)(b * NO1 + no) * 128 + q * 64 + lc) * 16 + part * 4;
        unsigned int* hl = (unsigned int*)Hbf;
#pragma unroll
        for (int j = 0; j < 4; j++) hl[lc * 20 + part * 4 + j] = hsrc[j];
    }

    size_t cbase = (size_t)(b * NO1 + no) * 128 * 32;
    float cst[4][2];
#pragma unroll
    for (int r = 0; r < 4; r++) {
        int gc = q * 64 + w * 16 + hg * 4 + r;
#pragma unroll
        for (int hi = 0; hi < 2; hi++)
            cst[r][hi] = c1g[cbase + (size_t)gc * 32 + lo + 16 * hi];
    }
    __syncthreads();

    float g8[8];
#pragma unroll
    for (int nt = 0; nt < 8; nt++) g8[nt] = gsh[lo + 16 * nt];
    const float* xfb = xf1T + (size_t)b * 128 * 128;
    f32x4 xf4[8];
#pragma unroll
    for (int nt = 0; nt < 8; nt++) {
        float4 x4 = *(const float4*)&xfb[(size_t)(lo + 16 * nt) * 128 + (q * 4 + w) * 16 + hg * 4];
        xf4[nt][0] = x4.x; xf4[nt][1] = x4.y; xf4[nt][2] = x4.z; xf4[nt][3] = x4.w;
    }

#pragma unroll
    for (int micro = 0; micro < 2; micro++) {
        bf16x8 A = *(const bf16x8*)&Hbf[(w * 16 + lo) * 40 + hg * 8];
        f32x4 acc[4];
#pragma unroll
        for (int g = 0; g < 4; g++) {
            int nt = 2 * g;
            bf16x8 B = *(const bf16x8*)&BW[(nt * 64 + l) * 8];
            f32x4 ci = xf4[nt] + g8[nt];
            acc[g] = __builtin_amdgcn_mfma_f32_16x16x32_bf16(A, B, ci, 0, 0, 0);
        }
#pragma unroll
        for (int r = 0; r < 4; r++) {
            int gc = q * 64 + w * 16 + hg * 4 + r;
            float cn = sigf(acc[1][r]) * cst[r][0] + sigf(acc[0][r]) * tanh_apx(acc[2][r]);
            cst[r][0] = cn;
            float hv = sigf(acc[3][r]) * tanh_apx(cn);
            unsigned short hb = f2bf(hv);
            Hbf[(w * 16 + hg * 4 + r) * 40 + lo] = hb;
            if (micro == 1) {
                h1bf[cbase + (size_t)gc * 32 + lo] = hb;
                c1g[cbase + (size_t)gc * 32 + lo] = cn;
            }
        }
#pragma unroll
        for (int g = 0; g < 4; g++) {
            int nt = 2 * g + 1;
            bf16x8 B = *(const bf16x8*)&BW[(nt * 64 + l) * 8];
            f32x4 ci = xf4[nt] + g8[nt];
            acc[g] = __builtin_amdgcn_mfma_f32_16x16x32_bf16(A, B, ci, 0, 0, 0);
        }
#pragma unroll
        for (int r = 0; r < 4; r++) {
            int gc = q * 64 + w * 16 + hg * 4 + r;
            float cn = sigf(acc[1][r]) * cst[r][1] + sigf(acc[0][r]) * tanh_apx(acc[2][r]);
            cst[r][1] = cn;
            float hv = sigf(acc[3][r]) * tanh_apx(cn);
            unsigned short hb = f2bf(hv);
            Hbf[(w * 16 + hg * 4 + r) * 40 + lo + 16] = hb;
            if (micro == 1) {
                h1bf[cbase + (size_t)gc * 32 + lo + 16] = hb;
                c1g[cbase + (size_t)gc * 32 + lo + 16] = cn;
            }
        }
    }

    // epilogue: fm (channel 0 -> outsum_part raw) and bm (-> bm_g)
    bf16x8 Ff = *(const bf16x8*)&BFr[l * 8];
    bf16x8 Bb = *(const bf16x8*)&BBr[l * 8];
    float lnfs = ln_fs[lo], lnfb = ln_fb[lo];
    float lnbs = ln_bs[lo], lnbb = ln_bb[lo];
    float bfv = bf_[lo], bwv = bwb[lo];
    f32x4 cif = {bfv, bfv, bfv, bfv};
    f32x4 cib = {bwv, bwv, bwv, bwv};
    float op = 0.f;
    {
        bf16x8 A = *(const bf16x8*)&Hbf[(w * 16 + lo) * 40 + hg * 8];
        f32x4 f = __builtin_amdgcn_mfma_f32_16x16x32_bf16(A, Ff, cif, 0, 0, 0);
        f32x4 g = __builtin_amdgcn_mfma_f32_16x16x32_bf16(A, Bb, cib, 0, 0, 0);
#pragma unroll
        for (int r = 0; r < 4; r++) {
            int gc = q * 64 + w * 16 + hg * 4 + r;
            {
                float x = f[r];
                float mean = sum16(x) * 0.0625f;
                float d = x - mean;
                float rs = rsqrtf(sum16(d * d) * 0.0625f + 1e-6f);
                op += d * rs * lnfs + lnfb;
            }
            {
                float x = g[r];
                float mean = sum16(x) * 0.0625f;
                float d = x - mean;
                float rs = rsqrtf(sum16(d * d) * 0.0625f + 1e-6f);
                bm_g[(((size_t)b * NO1 + no) * MSG + lo) * NI1 + gc] = d * rs * lnbs + lnbb;
            }
        }
    }
    op += __shfl_xor(op, 16);
    op += __shfl_xor(op, 32);
    if (l == 0) red[w] = op;
    __syncthreads();
    if (tid == 0)
        outsum_part[((size_t)b * NO1 + no) * 2 + q] = red[0] + red[1] + red[2] + red[3];
}

// ---------------------------------------------------------------------------
// k_post: fused k_red1 (blocks 0..63) + softmax/error (blocks 64..71)
// ---------------------------------------------------------------------------
__global__ __launch_bounds__(256) void k_post(
    const float* __restrict__ bm_g, float* __restrict__ nb1,
    const float* __restrict__ outsum_part, const int* __restrict__ labels,
    float* __restrict__ dout, float* __restrict__ gradP,
    float* __restrict__ ohP, int t) {
    if (blockIdx.x < 64) {
        int g = blockIdx.x * 256 + threadIdx.x;  // < 16384
        int ni = g & 127;
        int m = (g >> 7) & 15;
        int b = g >> 11;
        float a = 0.f;
#pragma unroll 8
        for (int no = 0; no < NO1; no++)
            a += bm_g[(((size_t)b * NO1 + no) * MSG + m) * NI1 + ni];
        nb1[((size_t)b * NI1 + ni) * MSG + m] = a * (1.f / NO1);
    } else {
        int b = blockIdx.x - 64;
        int no = threadIdx.x;
        if (no < 64) {
            float v = (outsum_part[((size_t)b * NO1 + no) * 2] +
                       outsum_part[((size_t)b * NO1 + no) * 2 + 1]) * (1.f / 128.f);
            float mx = v;
#pragma unroll
            for (int d = 1; d < 64; d <<= 1) mx = fmaxf(mx, __shfl_xor(mx, d));
            float e = __expf(v - mx);
            float sum = e;
#pragma unroll
            for (int d = 1; d < 64; d <<= 1) sum += __shfl_xor(sum, d);
            int lbl = labels[t * BATCH + b];
            float oh = (no == lbl) ? 1.f : 0.f;
            gradP[b * NO1 + no] = e / sum - oh;
            ohP[b * NO1 + no] = oh;
            dout[((size_t)t * BATCH + b) * NO1 + no] = v;
        }
    }
}

// ---------------------------------------------------------------------------

extern "C" void kernel_launch(void* const* d_in, const int* in_sizes, int n_in,
                              void* d_out, int out_size, void* d_ws, size_t ws_size,
                              hipStream_t stream) {
    const float* inp   = (const float*)d_in[0];
    const int*   labels= (const int*)d_in[1];
    const float* Wi    = (const float*)d_in[2];
    const float* Wh    = (const float*)d_in[3];
    const float* b_lstm= (const float*)d_in[4];
    const float* Wf    = (const float*)d_in[5];
    const float* bf_   = (const float*)d_in[6];
    const float* Wb    = (const float*)d_in[7];
    const float* bwb   = (const float*)d_in[8];
    const float* ln_fs = (const float*)d_in[9];
    const float* ln_fb = (const float*)d_in[10];
    const float* ln_bs = (const float*)d_in[11];
    const float* ln_bb = (const float*)d_in[12];
    float* out = (float*)d_out;

    const size_t SZ0 = (size_t)BATCH * NO0 * 256 * 32;  // 8,388,608
    const size_t SZ1 = (size_t)BATCH * NO1 * 128 * 32;  // 2,097,152

    // --- zero-init region (states + t=0 inputs) ---
    float* c0 = (float*)d_ws;
    float* c1 = c0 + SZ0;
    unsigned short* h0bf = (unsigned short*)(c1 + SZ1);
    unsigned short* h1bf = h0bf + SZ0;
    float* nb1   = (float*)(h1bf + SZ1);                // 8*128*16 = 16384
    float* gradP = nb1 + 16384;                         // 512
    float* ohP   = gradP + 512;                         // 512
    size_t zero_bytes = (size_t)((char*)(ohP + 512) - (char*)d_ws);
    // --- non-zeroed scratch ---
    float* xf1T  = ohP + 512;                           // 131072
    float* bm_g  = xf1T + 131072;                       // 1048576
    float* nfsum = bm_g + 1048576;                      // 16384
    float* outsum_part = nfsum + 16384;                 // 1024
    unsigned short* WhBp = (unsigned short*)(outsum_part + 1024);
    unsigned short* WfBp = WhBp + 4096;
    unsigned short* WbBp = WfBp + 512;

    hipMemsetAsync(d_ws, 0, zero_bytes, stream);
    k_prep<<<20, 256, 0, stream>>>(Wh, Wf, Wb, WhBp, WfBp, WbBp);

    for (int t = 0; t < TSTEPS; t++) {
        if (t) k_merge<<<1920, 256, 0, stream>>>((unsigned int*)h0bf, c0,
                                                 (unsigned int*)h1bf, c1);
        k_l0<<<BATCH * NO0, 256, 0, stream>>>(inp, Wi, WhBp, b_lstm, WfBp, bf_,
                                              ln_fs, ln_fb, h0bf, c0, nb1, nfsum, t);
        k_xf<<<BATCH * 128, 128, 0, stream>>>(nfsum, Wi, xf1T);
        k_l1<<<BATCH * NO1 * 2, 256, 0, stream>>>(Wi, WhBp, b_lstm, WfBp, bf_, ln_fs, ln_fb,
                                                  WbBp, bwb, ln_bs, ln_bb,
                                                  h1bf, c1, xf1T, gradP, ohP,
                                                  bm_g, outsum_part);
        k_post<<<72, 256, 0, stream>>>(bm_g, nb1, outsum_part, labels, out, gradP, ohP, t);
    }
}

// Round 11
// 318.985 us; speedup vs baseline: 1.7396x; 1.7396x over previous
//
#include <hip/hip_runtime.h>
#include <hip/hip_bf16.h>

#define SLOW 32
#define MSG 16
#define TSTEPS 4
#define BATCH 8
#define NI0 256
#define NO0 128
#define NI1 128
#define NO1 64

typedef __bf16 bf16x8 __attribute__((ext_vector_type(8)));
typedef float f32x4 __attribute__((ext_vector_type(4)));

__device__ __forceinline__ float rcpf(float x) { return __builtin_amdgcn_rcpf(x); }
__device__ __forceinline__ float sigf(float x) { return rcpf(1.f + __expf(-x)); }
__device__ __forceinline__ float tanh_apx(float x) {
    float xc = fminf(fmaxf(x, -15.f), 15.f);
    float e = __expf(-2.f * xc);
    return (1.f - e) * rcpf(1.f + e);
}
__device__ __forceinline__ unsigned short f2bf(float x) {
    __bf16 h = (__bf16)x;
    return __builtin_bit_cast(unsigned short, h);
}
__device__ __forceinline__ float bf2f(unsigned short u) {
    __bf16 h = __builtin_bit_cast(__bf16, u);
    return (float)h;
}
__device__ __forceinline__ float sum16(float v) {
    v += __shfl_xor(v, 1); v += __shfl_xor(v, 2);
    v += __shfl_xor(v, 4); v += __shfl_xor(v, 8);
    return v;
}

// ---------------------------------------------------------------------------
// k_prep: pack B-fragments (bf16) for Wh (8 n-tiles), Wf, Wb.
// frag slot (lane l, elem e) = W[k = (l>>4)*8 + e][col = nt*16 + (l&15)]
// ---------------------------------------------------------------------------
__global__ void k_prep(const float* __restrict__ Wh, const float* __restrict__ Wf,
                       const float* __restrict__ Wb,
                       unsigned short* __restrict__ WhBp,
                       unsigned short* __restrict__ WfBp,
                       unsigned short* __restrict__ WbBp) {
    int i = blockIdx.x * 256 + threadIdx.x;
    if (i < 4096) {
        int e = i & 7, l = (i >> 3) & 63, nt = i >> 9;
        int k = (l >> 4) * 8 + e, col = nt * 16 + (l & 15);
        WhBp[i] = f2bf(Wh[k * 128 + col]);
    } else if (i < 4608) {
        int j = i - 4096;
        int e = j & 7, l = j >> 3;
        int k = (l >> 4) * 8 + e;
        WfBp[j] = f2bf(Wf[k * 16 + (l & 15)]);
    } else if (i < 5120) {
        int j = i - 4608;
        int e = j & 7, l = j >> 3;
        int k = (l >> 4) * 8 + e;
        WbBp[j] = f2bf(Wb[k * 16 + (l & 15)]);
    }
}

// ---------------------------------------------------------------------------
// merge: mean over batch for slow channels s<16.
// layouts: h bf16 [b][no][cell][32], c f32 [b][no][cell][32]
// ---------------------------------------------------------------------------
__global__ void k_merge(unsigned int* __restrict__ h0, float* __restrict__ c0,
                        unsigned int* __restrict__ h1, float* __restrict__ c1) {
    int idx = blockIdx.x * 256 + threadIdx.x;
    if (idx < 262144) {  // l0 h
        int u = idx & 7, cell = (idx >> 3) & 255, no = idx >> 11;
        size_t base = ((size_t)no * 256 + cell) * 16 + u;
        const size_t strd = (size_t)128 * 256 * 16;
        float s0 = 0.f, s1 = 0.f;
#pragma unroll
        for (int b = 0; b < 8; b++) {
            unsigned int v = h0[base + b * strd];
            s0 += bf2f((unsigned short)(v & 0xffff));
            s1 += bf2f((unsigned short)(v >> 16));
        }
        unsigned int mv = (unsigned int)f2bf(s0 * 0.125f) |
                          ((unsigned int)f2bf(s1 * 0.125f) << 16);
#pragma unroll
        for (int b = 0; b < 8; b++) h0[base + b * strd] = mv;
        return;
    }
    idx -= 262144;
    if (idx < 131072) {  // l0 c
        int s4 = idx & 3, cell = (idx >> 2) & 255, no = idx >> 10;
        float4* C = (float4*)c0;
        size_t base = ((size_t)no * 256 + cell) * 8 + s4;
        const size_t strd = (size_t)128 * 256 * 8;
        float4 a = {0.f, 0.f, 0.f, 0.f};
#pragma unroll
        for (int b = 0; b < 8; b++) {
            float4 v = C[base + b * strd];
            a.x += v.x; a.y += v.y; a.z += v.z; a.w += v.w;
        }
        a.x *= 0.125f; a.y *= 0.125f; a.z *= 0.125f; a.w *= 0.125f;
#pragma unroll
        for (int b = 0; b < 8; b++) C[base + b * strd] = a;
        return;
    }
    idx -= 131072;
    if (idx < 65536) {  // l1 h
        int u = idx & 7, cell = (idx >> 3) & 127, no = idx >> 10;
        size_t base = ((size_t)no * 128 + cell) * 16 + u;
        const size_t strd = (size_t)64 * 128 * 16;
        float s0 = 0.f, s1 = 0.f;
#pragma unroll
        for (int b = 0; b < 8; b++) {
            unsigned int v = h1[base + b * strd];
            s0 += bf2f((unsigned short)(v & 0xffff));
            s1 += bf2f((unsigned short)(v >> 16));
        }
        unsigned int mv = (unsigned int)f2bf(s0 * 0.125f) |
                          ((unsigned int)f2bf(s1 * 0.125f) << 16);
#pragma unroll
        for (int b = 0; b < 8; b++) h1[base + b * strd] = mv;
        return;
    }
    idx -= 65536;
    if (idx < 32768) {  // l1 c
        int s4 = idx & 3, cell = (idx >> 2) & 127, no = idx >> 9;
        float4* C = (float4*)c1;
        size_t base = ((size_t)no * 128 + cell) * 8 + s4;
        const size_t strd = (size_t)64 * 128 * 8;
        float4 a = {0.f, 0.f, 0.f, 0.f};
#pragma unroll
        for (int b = 0; b < 8; b++) {
            float4 v = C[base + b * strd];
            a.x += v.x; a.y += v.y; a.z += v.z; a.w += v.w;
        }
        a.x *= 0.125f; a.y *= 0.125f; a.z *= 0.125f; a.w *= 0.125f;
#pragma unroll
        for (int b = 0; b < 8; b++) C[base + b * strd] = a;
    }
}

// ---------------------------------------------------------------------------
// Layer 0 (MFMA, half-block): block = (b,no,q), 4 waves, 128 cells,
// wave w owns 2 m-tiles (local rows 32w..32w+31). Barrier-free recurrence
// (cell-local LSTM; staging of wave's rows is wave-local too).
// NO register cap — r10 showed forced 64-VGPR => spills (WRITE 241MB).
// ---------------------------------------------------------------------------
__global__ __launch_bounds__(256) void k_l0(
    const float* __restrict__ inp, const float* __restrict__ Wi,
    const unsigned short* __restrict__ WhBp, const float* __restrict__ b_lstm,
    const unsigned short* __restrict__ WfBp, const float* __restrict__ bf_,
    const float* __restrict__ ln_fs, const float* __restrict__ ln_fb,
    unsigned short* __restrict__ h0bf, float* __restrict__ c0g,
    const float* __restrict__ nb1, float* __restrict__ nf_part, int t) {
    int q = blockIdx.x & 1;
    int no = (blockIdx.x >> 1) & 127;
    int b = blockIdx.x >> 8;
    int tid = threadIdx.x;
    int w = __builtin_amdgcn_readfirstlane(tid >> 6);
    int l = tid & 63, lo = l & 15, hg = l >> 4;

    __shared__ unsigned short Hbf[128 * 40];
    __shared__ unsigned short BW[4096];
    __shared__ unsigned short BFr[512];
    __shared__ float gsh[128];
    __shared__ float mi_l[128];
    __shared__ float wi0[128];
    __shared__ float redn[4][16];

    {
        unsigned int* d = (unsigned int*)BW;
        const unsigned int* s = (const unsigned int*)WhBp;
#pragma unroll
        for (int i = tid; i < 2048; i += 256) d[i] = s[i];
        ((unsigned int*)BFr)[tid] = ((const unsigned int*)WfBp)[tid];
    }
    if (tid < 128) {
        float acc = b_lstm[tid];
        const float* nbr = nb1 + ((size_t)b * NO0 + no) * MSG;
#pragma unroll
        for (int m = 0; m < MSG; m++) acc += nbr[m] * Wi[(MSG + m) * 128 + tid];
        gsh[tid] = acc;
        wi0[tid] = Wi[tid];
        mi_l[tid] = inp[((size_t)t * BATCH + b) * NI0 + q * 128 + tid];
    }

    // stage H (bf16): 2 threads per cell (wave-local rows: wave w -> 32w..)
    {
        int lc = tid >> 1, half = tid & 1;
        const unsigned int* hsrc =
            (const unsigned int*)h0bf +
            ((size_t)(b * NO0 + no) * 256 + q * 128 + lc) * 16 + half * 8;
        unsigned int* hl = (unsigned int*)Hbf;
#pragma unroll
        for (int j = 0; j < 8; j++) hl[lc * 20 + half * 8 + j] = hsrc[j];
    }

    size_t cbase = (size_t)(b * NO0 + no) * 256 * 32;
    float cst[2][4][2];
#pragma unroll
    for (int mi_ = 0; mi_ < 2; mi_++)
#pragma unroll
        for (int r = 0; r < 4; r++) {
            int gc = q * 128 + (w * 2 + mi_) * 16 + hg * 4 + r;
#pragma unroll
            for (int hi = 0; hi < 2; hi++)
                cst[mi_][r][hi] = c0g[cbase + (size_t)gc * 32 + lo + 16 * hi];
        }
    __syncthreads();  // BW/gsh/mi_l cooperative staging

    float g8[8], w8[8];
#pragma unroll
    for (int nt = 0; nt < 8; nt++) { g8[nt] = gsh[lo + 16 * nt]; w8[nt] = wi0[lo + 16 * nt]; }
    f32x4 miv[2];
#pragma unroll
    for (int mi_ = 0; mi_ < 2; mi_++)
#pragma unroll
        for (int r = 0; r < 4; r++)
            miv[mi_][r] = mi_l[(w * 2 + mi_) * 16 + hg * 4 + r];

#pragma unroll
    for (int micro = 0; micro < 2; micro++) {
#pragma unroll
        for (int mi_ = 0; mi_ < 2; mi_++) {
            int lt = w * 2 + mi_;                 // local m-tile
            bf16x8 A = *(const bf16x8*)&Hbf[(lt * 16 + lo) * 40 + hg * 8];
            f32x4 acc[4];
#pragma unroll
            for (int g = 0; g < 4; g++) {
                int nt = 2 * g;
                bf16x8 B = *(const bf16x8*)&BW[(nt * 64 + l) * 8];
                f32x4 ci = g8[nt] + miv[mi_] * w8[nt];
                acc[g] = __builtin_amdgcn_mfma_f32_16x16x32_bf16(A, B, ci, 0, 0, 0);
            }
#pragma unroll
            for (int r = 0; r < 4; r++) {
                int lrow = lt * 16 + hg * 4 + r;
                int gc = q * 128 + lrow;
                float cn = sigf(acc[1][r]) * cst[mi_][r][0] + sigf(acc[0][r]) * tanh_apx(acc[2][r]);
                cst[mi_][r][0] = cn;
                float hv = sigf(acc[3][r]) * tanh_apx(cn);
                unsigned short hb = f2bf(hv);
                Hbf[lrow * 40 + lo] = hb;
                if (micro == 1) {
                    h0bf[cbase + (size_t)gc * 32 + lo] = hb;
                    c0g[cbase + (size_t)gc * 32 + lo] = cn;
                }
            }
#pragma unroll
            for (int g = 0; g < 4; g++) {
                int nt = 2 * g + 1;
                bf16x8 B = *(const bf16x8*)&BW[(nt * 64 + l) * 8];
                f32x4 ci = g8[nt] + miv[mi_] * w8[nt];
                acc[g] = __builtin_amdgcn_mfma_f32_16x16x32_bf16(A, B, ci, 0, 0, 0);
            }
#pragma unroll
            for (int r = 0; r < 4; r++) {
                int lrow = lt * 16 + hg * 4 + r;
                int gc = q * 128 + lrow;
                float cn = sigf(acc[1][r]) * cst[mi_][r][1] + sigf(acc[0][r]) * tanh_apx(acc[2][r]);
                cst[mi_][r][1] = cn;
                float hv = sigf(acc[3][r]) * tanh_apx(cn);
                unsigned short hb = f2bf(hv);
                Hbf[lrow * 40 + lo + 16] = hb;
                if (micro == 1) {
                    h0bf[cbase + (size_t)gc * 32 + lo + 16] = hb;
                    c0g[cbase + (size_t)gc * 32 + lo + 16] = cn;
                }
            }
        }
        // no barrier: recurrence is wave-local
    }

    // epilogue: fm = LN(h @ Wf + bf); raw partial sums (k_xf divides /256)
    bf16x8 Ff = *(const bf16x8*)&BFr[l * 8];
    float lnfs = ln_fs[lo], lnfb = ln_fb[lo];
    float bfv = bf_[lo];
    f32x4 cif = {bfv, bfv, bfv, bfv};
    float nfp = 0.f;
#pragma unroll
    for (int mi_ = 0; mi_ < 2; mi_++) {
        int lt = w * 2 + mi_;
        bf16x8 A = *(const bf16x8*)&Hbf[(lt * 16 + lo) * 40 + hg * 8];
        f32x4 f = __builtin_amdgcn_mfma_f32_16x16x32_bf16(A, Ff, cif, 0, 0, 0);
#pragma unroll
        for (int r = 0; r < 4; r++) {
            float x = f[r];
            float mean = sum16(x) * 0.0625f;
            float d = x - mean;
            float rs = rsqrtf(sum16(d * d) * 0.0625f + 1e-6f);
            nfp += d * rs * lnfs + lnfb;
        }
    }
    nfp += __shfl_xor(nfp, 16);
    nfp += __shfl_xor(nfp, 32);
    if (l < 16) redn[w][l] = nfp;
    __syncthreads();
    if (tid < 16)
        nf_part[(((size_t)b * NO0 + no) * 2 + q) * 16 + tid] =
            redn[0][tid] + redn[1][tid] + redn[2][tid] + redn[3][tid];
}

// ---------------------------------------------------------------------------
// k_xf: xf1T[b][gate][ni] = sum_m nf[b,ni,m]/256 * Wi[m][gate]
// nf = sum of 2 half-block partials
// ---------------------------------------------------------------------------
__global__ __launch_bounds__(128) void k_xf(const float* __restrict__ nf_part,
                                            const float* __restrict__ Wi,
                                            float* __restrict__ xf1T) {
    int b = blockIdx.x >> 7;
    int k = blockIdx.x & 127;
    int no = threadIdx.x;
    float nf[MSG];
#pragma unroll
    for (int m = 0; m < MSG; m++) nf[m] = 0.f;
    const float* p = nf_part + ((size_t)b * NO0 + no) * 2 * MSG;
#pragma unroll
    for (int qm = 0; qm < 2 * MSG; qm++) nf[qm & 15] += p[qm];
    float a = 0.f;
#pragma unroll
    for (int m = 0; m < MSG; m++) a += nf[m] * Wi[m * 128 + k];
    xf1T[((size_t)b * 128 + k) * 128 + no] = a * (1.f / 256.f);
}

// ---------------------------------------------------------------------------
// Layer 1 (MFMA, split): block = (b,no1,q), 4 waves, 64 cells/block,
// wave w owns ONE m-tile. Barrier-free recurrence. No register cap.
// ---------------------------------------------------------------------------
__global__ __launch_bounds__(256) void k_l1(
    const float* __restrict__ Wi, const unsigned short* __restrict__ WhBp,
    const float* __restrict__ b_lstm,
    const unsigned short* __restrict__ WfBp, const float* __restrict__ bf_,
    const float* __restrict__ ln_fs, const float* __restrict__ ln_fb,
    const unsigned short* __restrict__ WbBp, const float* __restrict__ bwb,
    const float* __restrict__ ln_bs, const float* __restrict__ ln_bb,
    unsigned short* __restrict__ h1bf, float* __restrict__ c1g,
    const float* __restrict__ xf1T, const float* __restrict__ gradP,
    const float* __restrict__ ohP,
    float* __restrict__ bm_g, float* __restrict__ outsum_part) {
    int q = blockIdx.x & 1;
    int no = (blockIdx.x >> 1) & 63;
    int b = blockIdx.x >> 7;
    int tid = threadIdx.x;
    int w = __builtin_amdgcn_readfirstlane(tid >> 6);
    int l = tid & 63, lo = l & 15, hg = l >> 4;

    __shared__ unsigned short Hbf[64 * 40];
    __shared__ unsigned short BW[4096];
    __shared__ unsigned short BFr[512];
    __shared__ unsigned short BBr[512];
    __shared__ float gsh[128];
    __shared__ float red[4];

    {
        unsigned int* d = (unsigned int*)BW;
        const unsigned int* s = (const unsigned int*)WhBp;
#pragma unroll
        for (int i = tid; i < 2048; i += 256) d[i] = s[i];
        ((unsigned int*)BFr)[tid] = ((const unsigned int*)WfBp)[tid];
        ((unsigned int*)BBr)[tid] = ((const unsigned int*)WbBp)[tid];
    }
    if (tid < 128) {
        float g = gradP[b * NO1 + no], oh = ohP[b * NO1 + no];
        gsh[tid] = b_lstm[tid] + g * Wi[MSG * 128 + tid] + oh * Wi[(MSG + 1) * 128 + tid];
    }

    // stage H: cell lc = tid>>2, 4 u32 each (wave-local rows)
    {
        int lc = tid >> 2, part = tid & 3;
        const unsigned int* hsrc =
            (const unsigned int*)h1bf +
            ((size_t)(b * NO1 + no) * 128 + q * 64 + lc) * 16 + part * 4;
        unsigned int* hl = (unsigned int*)Hbf;
#pragma unroll
        for (int j = 0; j < 4; j++) hl[lc * 20 + part * 4 + j] = hsrc[j];
    }

    size_t cbase = (size_t)(b * NO1 + no) * 128 * 32;
    float cst[4][2];
#pragma unroll
    for (int r = 0; r < 4; r++) {
        int gc = q * 64 + w * 16 + hg * 4 + r;
#pragma unroll
        for (int hi = 0; hi < 2; hi++)
            cst[r][hi] = c1g[cbase + (size_t)gc * 32 + lo + 16 * hi];
    }
    __syncthreads();

    float g8[8];
#pragma unroll
    for (int nt = 0; nt < 8; nt++) g8[nt] = gsh[lo + 16 * nt];
    const float* xfb = xf1T + (size_t)b * 128 * 128;
    f32x4 xf4[8];
#pragma unroll
    for (int nt = 0; nt < 8; nt++) {
        float4 x4 = *(const float4*)&xfb[(size_t)(lo + 16 * nt) * 128 + (q * 4 + w) * 16 + hg * 4];
        xf4[nt][0] = x4.x; xf4[nt][1] = x4.y; xf4[nt][2] = x4.z; xf4[nt][3] = x4.w;
    }

#pragma unroll
    for (int micro = 0; micro < 2; micro++) {
        bf16x8 A = *(const bf16x8*)&Hbf[(w * 16 + lo) * 40 + hg * 8];
        f32x4 acc[4];
#pragma unroll
        for (int g = 0; g < 4; g++) {
            int nt = 2 * g;
            bf16x8 B = *(const bf16x8*)&BW[(nt * 64 + l) * 8];
            f32x4 ci = xf4[nt] + g8[nt];
            acc[g] = __builtin_amdgcn_mfma_f32_16x16x32_bf16(A, B, ci, 0, 0, 0);
        }
#pragma unroll
        for (int r = 0; r < 4; r++) {
            int gc = q * 64 + w * 16 + hg * 4 + r;
            float cn = sigf(acc[1][r]) * cst[r][0] + sigf(acc[0][r]) * tanh_apx(acc[2][r]);
            cst[r][0] = cn;
            float hv = sigf(acc[3][r]) * tanh_apx(cn);
            unsigned short hb = f2bf(hv);
            Hbf[(w * 16 + hg * 4 + r) * 40 + lo] = hb;
            if (micro == 1) {
                h1bf[cbase + (size_t)gc * 32 + lo] = hb;
                c1g[cbase + (size_t)gc * 32 + lo] = cn;
            }
        }
#pragma unroll
        for (int g = 0; g < 4; g++) {
            int nt = 2 * g + 1;
            bf16x8 B = *(const bf16x8*)&BW[(nt * 64 + l) * 8];
            f32x4 ci = xf4[nt] + g8[nt];
            acc[g] = __builtin_amdgcn_mfma_f32_16x16x32_bf16(A, B, ci, 0, 0, 0);
        }
#pragma unroll
        for (int r = 0; r < 4; r++) {
            int gc = q * 64 + w * 16 + hg * 4 + r;
            float cn = sigf(acc[1][r]) * cst[r][1] + sigf(acc[0][r]) * tanh_apx(acc[2][r]);
            cst[r][1] = cn;
            float hv = sigf(acc[3][r]) * tanh_apx(cn);
            unsigned short hb = f2bf(hv);
            Hbf[(w * 16 + hg * 4 + r) * 40 + lo + 16] = hb;
            if (micro == 1) {
                h1bf[cbase + (size_t)gc * 32 + lo + 16] = hb;
                c1g[cbase + (size_t)gc * 32 + lo + 16] = cn;
            }
        }
    }

    // epilogue: fm (channel 0 -> outsum_part raw) and bm (-> bm_g)
    bf16x8 Ff = *(const bf16x8*)&BFr[l * 8];
    bf16x8 Bb = *(const bf16x8*)&BBr[l * 8];
    float lnfs = ln_fs[lo], lnfb = ln_fb[lo];
    float lnbs = ln_bs[lo], lnbb = ln_bb[lo];
    float bfv = bf_[lo], bwv = bwb[lo];
    f32x4 cif = {bfv, bfv, bfv, bfv};
    f32x4 cib = {bwv, bwv, bwv, bwv};
    float op = 0.f;
    {
        bf16x8 A = *(const bf16x8*)&Hbf[(w * 16 + lo) * 40 + hg * 8];
        f32x4 f = __builtin_amdgcn_mfma_f32_16x16x32_bf16(A, Ff, cif, 0, 0, 0);
        f32x4 g = __builtin_amdgcn_mfma_f32_16x16x32_bf16(A, Bb, cib, 0, 0, 0);
#pragma unroll
        for (int r = 0; r < 4; r++) {
            int gc = q * 64 + w * 16 + hg * 4 + r;
            {
                float x = f[r];
                float mean = sum16(x) * 0.0625f;
                float d = x - mean;
                float rs = rsqrtf(sum16(d * d) * 0.0625f + 1e-6f);
                op += d * rs * lnfs + lnfb;
            }
            {
                float x = g[r];
                float mean = sum16(x) * 0.0625f;
                float d = x - mean;
                float rs = rsqrtf(sum16(d * d) * 0.0625f + 1e-6f);
                bm_g[(((size_t)b * NO1 + no) * MSG + lo) * NI1 + gc] = d * rs * lnbs + lnbb;
            }
        }
    }
    op += __shfl_xor(op, 16);
    op += __shfl_xor(op, 32);
    if (l == 0) red[w] = op;
    __syncthreads();
    if (tid == 0)
        outsum_part[((size_t)b * NO1 + no) * 2 + q] = red[0] + red[1] + red[2] + red[3];
}

// ---------------------------------------------------------------------------
// k_post: fused nb1 reduction (blocks 0..63) + softmax/error (blocks 64..71)
// ---------------------------------------------------------------------------
__global__ __launch_bounds__(256) void k_post(
    const float* __restrict__ bm_g, float* __restrict__ nb1,
    const float* __restrict__ outsum_part, const int* __restrict__ labels,
    float* __restrict__ dout, float* __restrict__ gradP,
    float* __restrict__ ohP, int t) {
    if (blockIdx.x < 64) {
        int g = blockIdx.x * 256 + threadIdx.x;  // < 16384
        int ni = g & 127;
        int m = (g >> 7) & 15;
        int b = g >> 11;
        float a = 0.f;
#pragma unroll 8
        for (int no = 0; no < NO1; no++)
            a += bm_g[(((size_t)b * NO1 + no) * MSG + m) * NI1 + ni];
        nb1[((size_t)b * NI1 + ni) * MSG + m] = a * (1.f / NO1);
    } else {
        int b = blockIdx.x - 64;
        int no = threadIdx.x;
        if (no < 64) {
            float v = (outsum_part[((size_t)b * NO1 + no) * 2] +
                       outsum_part[((size_t)b * NO1 + no) * 2 + 1]) * (1.f / 128.f);
            float mx = v;
#pragma unroll
            for (int d = 1; d < 64; d <<= 1) mx = fmaxf(mx, __shfl_xor(mx, d));
            float e = __expf(v - mx);
            float sum = e;
#pragma unroll
            for (int d = 1; d < 64; d <<= 1) sum += __shfl_xor(sum, d);
            int lbl = labels[t * BATCH + b];
            float oh = (no == lbl) ? 1.f : 0.f;
            gradP[b * NO1 + no] = e / sum - oh;
            ohP[b * NO1 + no] = oh;
            dout[((size_t)t * BATCH + b) * NO1 + no] = v;
        }
    }
}

// ---------------------------------------------------------------------------

extern "C" void kernel_launch(void* const* d_in, const int* in_sizes, int n_in,
                              void* d_out, int out_size, void* d_ws, size_t ws_size,
                              hipStream_t stream) {
    const float* inp   = (const float*)d_in[0];
    const int*   labels= (const int*)d_in[1];
    const float* Wi    = (const float*)d_in[2];
    const float* Wh    = (const float*)d_in[3];
    const float* b_lstm= (const float*)d_in[4];
    const float* Wf    = (const float*)d_in[5];
    const float* bf_   = (const float*)d_in[6];
    const float* Wb    = (const float*)d_in[7];
    const float* bwb   = (const float*)d_in[8];
    const float* ln_fs = (const float*)d_in[9];
    const float* ln_fb = (const float*)d_in[10];
    const float* ln_bs = (const float*)d_in[11];
    const float* ln_bb = (const float*)d_in[12];
    float* out = (float*)d_out;

    const size_t SZ0 = (size_t)BATCH * NO0 * 256 * 32;  // 8,388,608
    const size_t SZ1 = (size_t)BATCH * NO1 * 128 * 32;  // 2,097,152

    // --- zero-init region (states + first-step msg inputs) ---
    float* c0 = (float*)d_ws;
    float* c1 = c0 + SZ0;
    unsigned short* h0bf = (unsigned short*)(c1 + SZ1);
    unsigned short* h1bf = h0bf + SZ0;
    float* nb1   = (float*)(h1bf + SZ1);                // 16384
    float* gradP = nb1 + 16384;                         // 512
    float* ohP   = gradP + 512;                         // 512
    size_t zero_bytes = (size_t)((char*)(ohP + 512) - (char*)d_ws);
    // --- non-zeroed scratch ---
    float* xf1T  = ohP + 512;                           // 131072
    float* bm_g  = xf1T + 131072;                       // 1048576
    float* nf_part = bm_g + 1048576;                    // 32768
    float* outsum_part = nf_part + 32768;               // 1024
    unsigned short* WhBp = (unsigned short*)(outsum_part + 1024);
    unsigned short* WfBp = WhBp + 4096;
    unsigned short* WbBp = WfBp + 512;

    hipMemsetAsync(d_ws, 0, zero_bytes, stream);
    k_prep<<<20, 256, 0, stream>>>(Wh, Wf, Wb, WhBp, WfBp, WbBp);

    for (int t = 0; t < TSTEPS; t++) {
        if (t) k_merge<<<1920, 256, 0, stream>>>((unsigned int*)h0bf, c0,
                                                 (unsigned int*)h1bf, c1);
        k_l0<<<BATCH * NO0 * 2, 256, 0, stream>>>(inp, Wi, WhBp, b_lstm, WfBp, bf_,
                                                  ln_fs, ln_fb, h0bf, c0, nb1, nf_part, t);
        k_xf<<<BATCH * 128, 128, 0, stream>>>(nf_part, Wi, xf1T);
        k_l1<<<BATCH * NO1 * 2, 256, 0, stream>>>(Wi, WhBp, b_lstm, WfBp, bf_, ln_fs, ln_fb,
                                                  WbBp, bwb, ln_bs, ln_bb,
                                                  h1bf, c1, xf1T, gradP, ohP,
                                                  bm_g, outsum_part);
        k_post<<<72, 256, 0, stream>>>(bm_g, nb1, outsum_part, labels, out, gradP, ohP, t);
    }
}

// Round 12
// 305.741 us; speedup vs baseline: 1.8149x; 1.0433x over previous
//
#include <hip/hip_runtime.h>
#include <hip/hip_bf16.h>

#define SLOW 32
#define MSG 16
#define TSTEPS 4
#define BATCH 8
#define NI0 256
#define NO0 128
#define NI1 128
#define NO1 64

typedef __bf16 bf16x8 __attribute__((ext_vector_type(8)));
typedef float f32x4 __attribute__((ext_vector_type(4)));

__device__ __forceinline__ float rcpf(float x) { return __builtin_amdgcn_rcpf(x); }
__device__ __forceinline__ float sigf(float x) { return rcpf(1.f + __expf(-x)); }
__device__ __forceinline__ float tanh_apx(float x) {
    float xc = fminf(fmaxf(x, -15.f), 15.f);
    float e = __expf(-2.f * xc);
    return (1.f - e) * rcpf(1.f + e);
}
__device__ __forceinline__ unsigned short f2bf(float x) {
    __bf16 h = (__bf16)x;
    return __builtin_bit_cast(unsigned short, h);
}
__device__ __forceinline__ float bf2f(unsigned short u) {
    __bf16 h = __builtin_bit_cast(__bf16, u);
    return (float)h;
}
__device__ __forceinline__ float sum16(float v) {
    v += __shfl_xor(v, 1); v += __shfl_xor(v, 2);
    v += __shfl_xor(v, 4); v += __shfl_xor(v, 8);
    return v;
}

// ---------------------------------------------------------------------------
// k_prep: pack B-fragments (bf16) for Wh (8 nt), Wf, Wb, and Wi-fwd (8 nt,
// K zero-padded 16->32). slot (lane l, elem e) = W[k=(l>>4)*8+e][nt*16+(l&15)]
// ---------------------------------------------------------------------------
__global__ void k_prep(const float* __restrict__ Wh, const float* __restrict__ Wf,
                       const float* __restrict__ Wb, const float* __restrict__ Wi,
                       unsigned short* __restrict__ WhBp,
                       unsigned short* __restrict__ WfBp,
                       unsigned short* __restrict__ WbBp,
                       unsigned short* __restrict__ WiFp) {
    int i = blockIdx.x * 256 + threadIdx.x;
    if (i < 4096) {
        int e = i & 7, l = (i >> 3) & 63, nt = i >> 9;
        int k = (l >> 4) * 8 + e, col = nt * 16 + (l & 15);
        WhBp[i] = f2bf(Wh[k * 128 + col]);
    } else if (i < 4608) {
        int j = i - 4096;
        int e = j & 7, l = j >> 3;
        int k = (l >> 4) * 8 + e;
        WfBp[j] = f2bf(Wf[k * 16 + (l & 15)]);
    } else if (i < 5120) {
        int j = i - 4608;
        int e = j & 7, l = j >> 3;
        int k = (l >> 4) * 8 + e;
        WbBp[j] = f2bf(Wb[k * 16 + (l & 15)]);
    } else if (i < 9216) {
        int j = i - 5120;
        int e = j & 7, l = (j >> 3) & 63, nt = j >> 9;
        int k = (l >> 4) * 8 + e, col = nt * 16 + (l & 15);
        WiFp[j] = (k < 16) ? f2bf(Wi[k * 128 + col]) : (unsigned short)0;
    }
}

// ---------------------------------------------------------------------------
// merge: mean over batch for slow channels s<16 (in place).
// h bf16 [b][no][cell][32], c f32 [b][no][cell][32]
// ---------------------------------------------------------------------------
__global__ void k_merge(unsigned int* __restrict__ h0, float* __restrict__ c0,
                        unsigned int* __restrict__ h1, float* __restrict__ c1) {
    int idx = blockIdx.x * 256 + threadIdx.x;
    if (idx < 262144) {  // l0 h
        int u = idx & 7, cell = (idx >> 3) & 255, no = idx >> 11;
        size_t base = ((size_t)no * 256 + cell) * 16 + u;
        const size_t strd = (size_t)128 * 256 * 16;
        float s0 = 0.f, s1 = 0.f;
#pragma unroll
        for (int b = 0; b < 8; b++) {
            unsigned int v = h0[base + b * strd];
            s0 += bf2f((unsigned short)(v & 0xffff));
            s1 += bf2f((unsigned short)(v >> 16));
        }
        unsigned int mv = (unsigned int)f2bf(s0 * 0.125f) |
                          ((unsigned int)f2bf(s1 * 0.125f) << 16);
#pragma unroll
        for (int b = 0; b < 8; b++) h0[base + b * strd] = mv;
        return;
    }
    idx -= 262144;
    if (idx < 131072) {  // l0 c
        int s4 = idx & 3, cell = (idx >> 2) & 255, no = idx >> 10;
        float4* C = (float4*)c0;
        size_t base = ((size_t)no * 256 + cell) * 8 + s4;
        const size_t strd = (size_t)128 * 256 * 8;
        float4 a = {0.f, 0.f, 0.f, 0.f};
#pragma unroll
        for (int b = 0; b < 8; b++) {
            float4 v = C[base + b * strd];
            a.x += v.x; a.y += v.y; a.z += v.z; a.w += v.w;
        }
        a.x *= 0.125f; a.y *= 0.125f; a.z *= 0.125f; a.w *= 0.125f;
#pragma unroll
        for (int b = 0; b < 8; b++) C[base + b * strd] = a;
        return;
    }
    idx -= 131072;
    if (idx < 65536) {  // l1 h
        int u = idx & 7, cell = (idx >> 3) & 127, no = idx >> 10;
        size_t base = ((size_t)no * 128 + cell) * 16 + u;
        const size_t strd = (size_t)64 * 128 * 16;
        float s0 = 0.f, s1 = 0.f;
#pragma unroll
        for (int b = 0; b < 8; b++) {
            unsigned int v = h1[base + b * strd];
            s0 += bf2f((unsigned short)(v & 0xffff));
            s1 += bf2f((unsigned short)(v >> 16));
        }
        unsigned int mv = (unsigned int)f2bf(s0 * 0.125f) |
                          ((unsigned int)f2bf(s1 * 0.125f) << 16);
#pragma unroll
        for (int b = 0; b < 8; b++) h1[base + b * strd] = mv;
        return;
    }
    idx -= 65536;
    if (idx < 32768) {  // l1 c
        int s4 = idx & 3, cell = (idx >> 2) & 127, no = idx >> 9;
        float4* C = (float4*)c1;
        size_t base = ((size_t)no * 128 + cell) * 8 + s4;
        const size_t strd = (size_t)64 * 128 * 8;
        float4 a = {0.f, 0.f, 0.f, 0.f};
#pragma unroll
        for (int b = 0; b < 8; b++) {
            float4 v = C[base + b * strd];
            a.x += v.x; a.y += v.y; a.z += v.z; a.w += v.w;
        }
        a.x *= 0.125f; a.y *= 0.125f; a.z *= 0.125f; a.w *= 0.125f;
#pragma unroll
        for (int b = 0; b < 8; b++) C[base + b * strd] = a;
    }
}

// ---------------------------------------------------------------------------
// Layer 0: block = (b,no,q), 4 waves, 128 cells, wave w owns 2 m-tiles.
// t==0: states are zero (no loads, no memset needed). nb1-reduce from bm_g
// folded into prologue (wave 0). h writeback = one coalesced bulk copy.
// ---------------------------------------------------------------------------
__global__ __launch_bounds__(256) void k_l0(
    const float* __restrict__ inp, const float* __restrict__ Wi,
    const unsigned short* __restrict__ WhBp, const float* __restrict__ b_lstm,
    const unsigned short* __restrict__ WfBp, const float* __restrict__ bf_,
    const float* __restrict__ ln_fs, const float* __restrict__ ln_fb,
    unsigned short* __restrict__ h0bf, float* __restrict__ c0g,
    const float* __restrict__ bm_g, float* __restrict__ nf_part, int t) {
    int q = blockIdx.x & 1;
    int no = (blockIdx.x >> 1) & 127;
    int b = blockIdx.x >> 8;
    int tid = threadIdx.x;
    int w = __builtin_amdgcn_readfirstlane(tid >> 6);
    int l = tid & 63, lo = l & 15, hg = l >> 4;

    __shared__ unsigned short Hbf[128 * 40];
    __shared__ unsigned short BW[4096];
    __shared__ unsigned short BFr[512];
    __shared__ float gsh[128];
    __shared__ float mi_l[128];
    __shared__ float wi0[128];
    __shared__ float redn[4][16];
    __shared__ float nbv[16];

    // ---- phase 1: staging ----
    {
        unsigned int* d = (unsigned int*)BW;
        const unsigned int* s = (const unsigned int*)WhBp;
#pragma unroll
        for (int i = tid; i < 2048; i += 256) d[i] = s[i];
        ((unsigned int*)BFr)[tid] = ((const unsigned int*)WfBp)[tid];
    }
    if (tid < 128) {
        wi0[tid] = Wi[tid];
        mi_l[tid] = inp[((size_t)t * BATCH + b) * NI0 + q * 128 + tid];
    }
    {
        int lc = tid >> 1, half = tid & 1;
        unsigned int* hl = (unsigned int*)Hbf;
        if (t > 0) {
            const unsigned int* hsrc =
                (const unsigned int*)h0bf +
                ((size_t)(b * NO0 + no) * 256 + q * 128 + lc) * 16 + half * 8;
#pragma unroll
            for (int j = 0; j < 8; j++) hl[lc * 20 + half * 8 + j] = hsrc[j];
        } else {
#pragma unroll
            for (int j = 0; j < 8; j++) hl[lc * 20 + half * 8 + j] = 0u;
        }
    }
    size_t cbase = (size_t)(b * NO0 + no) * 256 * 32;
    float cst[2][4][2];
    if (t > 0) {
#pragma unroll
        for (int mi_ = 0; mi_ < 2; mi_++)
#pragma unroll
            for (int r = 0; r < 4; r++) {
                int gc = q * 128 + (w * 2 + mi_) * 16 + hg * 4 + r;
#pragma unroll
                for (int hi = 0; hi < 2; hi++)
                    cst[mi_][r][hi] = c0g[cbase + (size_t)gc * 32 + lo + 16 * hi];
            }
    } else {
#pragma unroll
        for (int mi_ = 0; mi_ < 2; mi_++)
#pragma unroll
            for (int r = 0; r < 4; r++) { cst[mi_][r][0] = 0.f; cst[mi_][r][1] = 0.f; }
    }
    // nb[m] = mean over no1 of bm_g[b][no1][m][no]  (wave 0 only)
    if (t > 0 && w == 0) {
        int m = l >> 2, part = l & 3;
        float a = 0.f;
#pragma unroll 4
        for (int j = 0; j < 16; j++)
            a += bm_g[(((size_t)b * 64 + part * 16 + j) * 16 + m) * 128 + no];
        a += __shfl_xor(a, 1);
        a += __shfl_xor(a, 2);
        if (part == 0) nbv[m] = a * (1.f / 64.f);
    }
    __syncthreads();

    // ---- phase 2: gsh ----
    if (tid < 128) {
        float acc = b_lstm[tid];
        if (t > 0) {
#pragma unroll
            for (int m = 0; m < MSG; m++) acc += nbv[m] * Wi[(MSG + m) * 128 + tid];
        }
        gsh[tid] = acc;
    }
    __syncthreads();

    float g8[8], w8[8];
#pragma unroll
    for (int nt = 0; nt < 8; nt++) { g8[nt] = gsh[lo + 16 * nt]; w8[nt] = wi0[lo + 16 * nt]; }
    f32x4 miv[2];
#pragma unroll
    for (int mi_ = 0; mi_ < 2; mi_++)
#pragma unroll
        for (int r = 0; r < 4; r++)
            miv[mi_][r] = mi_l[(w * 2 + mi_) * 16 + hg * 4 + r];

#pragma unroll
    for (int micro = 0; micro < 2; micro++) {
#pragma unroll
        for (int mi_ = 0; mi_ < 2; mi_++) {
            int lt = w * 2 + mi_;
            bf16x8 A = *(const bf16x8*)&Hbf[(lt * 16 + lo) * 40 + hg * 8];
            f32x4 acc[4];
#pragma unroll
            for (int g = 0; g < 4; g++) {
                int nt = 2 * g;
                bf16x8 B = *(const bf16x8*)&BW[(nt * 64 + l) * 8];
                f32x4 ci = g8[nt] + miv[mi_] * w8[nt];
                acc[g] = __builtin_amdgcn_mfma_f32_16x16x32_bf16(A, B, ci, 0, 0, 0);
            }
#pragma unroll
            for (int r = 0; r < 4; r++) {
                int lrow = lt * 16 + hg * 4 + r;
                float cn = sigf(acc[1][r]) * cst[mi_][r][0] + sigf(acc[0][r]) * tanh_apx(acc[2][r]);
                cst[mi_][r][0] = cn;
                float hv = sigf(acc[3][r]) * tanh_apx(cn);
                Hbf[lrow * 40 + lo] = f2bf(hv);
                if (micro == 1)
                    c0g[cbase + (size_t)(q * 128 + lrow) * 32 + lo] = cn;
            }
#pragma unroll
            for (int g = 0; g < 4; g++) {
                int nt = 2 * g + 1;
                bf16x8 B = *(const bf16x8*)&BW[(nt * 64 + l) * 8];
                f32x4 ci = g8[nt] + miv[mi_] * w8[nt];
                acc[g] = __builtin_amdgcn_mfma_f32_16x16x32_bf16(A, B, ci, 0, 0, 0);
            }
#pragma unroll
            for (int r = 0; r < 4; r++) {
                int lrow = lt * 16 + hg * 4 + r;
                float cn = sigf(acc[1][r]) * cst[mi_][r][1] + sigf(acc[0][r]) * tanh_apx(acc[2][r]);
                cst[mi_][r][1] = cn;
                float hv = sigf(acc[3][r]) * tanh_apx(cn);
                Hbf[lrow * 40 + lo + 16] = f2bf(hv);
                if (micro == 1)
                    c0g[cbase + (size_t)(q * 128 + lrow) * 32 + lo + 16] = cn;
            }
        }
        // no barrier: recurrence is wave-local
    }

    // epilogue: fm = LN(h @ Wf + bf); raw partial sums
    bf16x8 Ff = *(const bf16x8*)&BFr[l * 8];
    float lnfs = ln_fs[lo], lnfb = ln_fb[lo];
    float bfv = bf_[lo];
    f32x4 cif = {bfv, bfv, bfv, bfv};
    float nfp = 0.f;
#pragma unroll
    for (int mi_ = 0; mi_ < 2; mi_++) {
        int lt = w * 2 + mi_;
        bf16x8 A = *(const bf16x8*)&Hbf[(lt * 16 + lo) * 40 + hg * 8];
        f32x4 f = __builtin_amdgcn_mfma_f32_16x16x32_bf16(A, Ff, cif, 0, 0, 0);
#pragma unroll
        for (int r = 0; r < 4; r++) {
            float x = f[r];
            float mean = sum16(x) * 0.0625f;
            float d = x - mean;
            float rs = rsqrtf(sum16(d * d) * 0.0625f + 1e-6f);
            nfp += d * rs * lnfs + lnfb;
        }
    }
    nfp += __shfl_xor(nfp, 16);
    nfp += __shfl_xor(nfp, 32);
    if (l < 16) redn[w][l] = nfp;
    __syncthreads();
    if (tid < 16)
        nf_part[(((size_t)b * NO0 + no) * 2 + q) * 16 + tid] =
            redn[0][tid] + redn[1][tid] + redn[2][tid] + redn[3][tid];

    // bulk coalesced h writeback (all waves' Hbf writes done before the sync)
    {
        int lc = tid >> 1, part = tid & 1;
        unsigned int* hdst =
            (unsigned int*)h0bf +
            ((size_t)(b * NO0 + no) * 256 + q * 128 + lc) * 16 + part * 8;
        const unsigned int* hl = (const unsigned int*)Hbf;
#pragma unroll
        for (int j = 0; j < 8; j++) hdst[j] = hl[lc * 20 + part * 8 + j];
    }
}

// ---------------------------------------------------------------------------
// Layer 1: block = (b,no1,q), 4 waves, 64 cells, wave w owns ONE m-tile.
// xf computed in-kernel via MFMA (nf bf16 A-frag x prepacked Wi-fwd B-frag).
// t==0: zero states, zero grad/oh.
// ---------------------------------------------------------------------------
__global__ __launch_bounds__(256) void k_l1(
    const float* __restrict__ Wi, const unsigned short* __restrict__ WhBp,
    const float* __restrict__ b_lstm,
    const unsigned short* __restrict__ WfBp, const float* __restrict__ bf_,
    const float* __restrict__ ln_fs, const float* __restrict__ ln_fb,
    const unsigned short* __restrict__ WbBp, const float* __restrict__ bwb,
    const float* __restrict__ ln_bs, const float* __restrict__ ln_bb,
    const unsigned short* __restrict__ WiFp,
    unsigned short* __restrict__ h1bf, float* __restrict__ c1g,
    const float* __restrict__ nf_part, const float* __restrict__ gradP,
    const float* __restrict__ ohP,
    float* __restrict__ bm_g, float* __restrict__ outsum_part, int t) {
    int q = blockIdx.x & 1;
    int no = (blockIdx.x >> 1) & 63;
    int b = blockIdx.x >> 7;
    int tid = threadIdx.x;
    int w = __builtin_amdgcn_readfirstlane(tid >> 6);
    int l = tid & 63, lo = l & 15, hg = l >> 4;

    __shared__ unsigned short Hbf[64 * 40];
    __shared__ unsigned short BW[4096];
    __shared__ unsigned short WiF[4096];
    __shared__ unsigned short BFr[512];
    __shared__ unsigned short BBr[512];
    __shared__ float gsh[128];
    __shared__ float red[4];

    // ---- staging ----
    {
        unsigned int* d = (unsigned int*)BW;
        const unsigned int* s = (const unsigned int*)WhBp;
        unsigned int* d2 = (unsigned int*)WiF;
        const unsigned int* s2 = (const unsigned int*)WiFp;
#pragma unroll
        for (int i = tid; i < 2048; i += 256) { d[i] = s[i]; d2[i] = s2[i]; }
        ((unsigned int*)BFr)[tid] = ((const unsigned int*)WfBp)[tid];
        ((unsigned int*)BBr)[tid] = ((const unsigned int*)WbBp)[tid];
    }
    if (tid < 128) {
        float acc = b_lstm[tid];
        if (t > 0) {
            float g = gradP[b * NO1 + no], oh = ohP[b * NO1 + no];
            acc += g * Wi[MSG * 128 + tid] + oh * Wi[(MSG + 1) * 128 + tid];
        }
        gsh[tid] = acc;
    }
    {
        int lc = tid >> 2, part = tid & 3;
        unsigned int* hl = (unsigned int*)Hbf;
        if (t > 0) {
            const unsigned int* hsrc =
                (const unsigned int*)h1bf +
                ((size_t)(b * NO1 + no) * 128 + q * 64 + lc) * 16 + part * 4;
#pragma unroll
            for (int j = 0; j < 4; j++) hl[lc * 20 + part * 4 + j] = hsrc[j];
        } else {
#pragma unroll
            for (int j = 0; j < 4; j++) hl[lc * 20 + part * 4 + j] = 0u;
        }
    }
    size_t cbase = (size_t)(b * NO1 + no) * 128 * 32;
    float cst[4][2];
    if (t > 0) {
#pragma unroll
        for (int r = 0; r < 4; r++) {
            int gc = q * 64 + w * 16 + hg * 4 + r;
#pragma unroll
            for (int hi = 0; hi < 2; hi++)
                cst[r][hi] = c1g[cbase + (size_t)gc * 32 + lo + 16 * hi];
        }
    } else {
#pragma unroll
        for (int r = 0; r < 4; r++) { cst[r][0] = 0.f; cst[r][1] = 0.f; }
    }
    // A-fragment of nf (bf16): row = cell (w*16+lo), k = m (hg<2), else 0
    bf16x8 Anf;
#pragma unroll
    for (int e = 0; e < 8; e++) Anf[e] = (__bf16)0.f;
    if (hg < 2) {
        const float* p = nf_part +
            ((size_t)b * 128 + q * 64 + w * 16 + lo) * 32 + hg * 8;
#pragma unroll
        for (int e = 0; e < 8; e++)
            Anf[e] = (__bf16)((p[e] + p[e + 16]) * (1.f / 256.f));
    }
    __syncthreads();

    // xf via MFMA: D[nt] -> row = cell(hg*4+r), col = gate(lo+16nt)
    f32x4 xf4[8];
    {
        f32x4 zz = {0.f, 0.f, 0.f, 0.f};
#pragma unroll
        for (int nt = 0; nt < 8; nt++) {
            bf16x8 B = *(const bf16x8*)&WiF[(nt * 64 + l) * 8];
            xf4[nt] = __builtin_amdgcn_mfma_f32_16x16x32_bf16(Anf, B, zz, 0, 0, 0);
        }
    }
    float g8[8];
#pragma unroll
    for (int nt = 0; nt < 8; nt++) g8[nt] = gsh[lo + 16 * nt];

#pragma unroll
    for (int micro = 0; micro < 2; micro++) {
        bf16x8 A = *(const bf16x8*)&Hbf[(w * 16 + lo) * 40 + hg * 8];
        f32x4 acc[4];
#pragma unroll
        for (int g = 0; g < 4; g++) {
            int nt = 2 * g;
            bf16x8 B = *(const bf16x8*)&BW[(nt * 64 + l) * 8];
            f32x4 ci = xf4[nt] + g8[nt];
            acc[g] = __builtin_amdgcn_mfma_f32_16x16x32_bf16(A, B, ci, 0, 0, 0);
        }
#pragma unroll
        for (int r = 0; r < 4; r++) {
            float cn = sigf(acc[1][r]) * cst[r][0] + sigf(acc[0][r]) * tanh_apx(acc[2][r]);
            cst[r][0] = cn;
            float hv = sigf(acc[3][r]) * tanh_apx(cn);
            Hbf[(w * 16 + hg * 4 + r) * 40 + lo] = f2bf(hv);
            if (micro == 1)
                c1g[cbase + (size_t)(q * 64 + w * 16 + hg * 4 + r) * 32 + lo] = cn;
        }
#pragma unroll
        for (int g = 0; g < 4; g++) {
            int nt = 2 * g + 1;
            bf16x8 B = *(const bf16x8*)&BW[(nt * 64 + l) * 8];
            f32x4 ci = xf4[nt] + g8[nt];
            acc[g] = __builtin_amdgcn_mfma_f32_16x16x32_bf16(A, B, ci, 0, 0, 0);
        }
#pragma unroll
        for (int r = 0; r < 4; r++) {
            float cn = sigf(acc[1][r]) * cst[r][1] + sigf(acc[0][r]) * tanh_apx(acc[2][r]);
            cst[r][1] = cn;
            float hv = sigf(acc[3][r]) * tanh_apx(cn);
            Hbf[(w * 16 + hg * 4 + r) * 40 + lo + 16] = f2bf(hv);
            if (micro == 1)
                c1g[cbase + (size_t)(q * 64 + w * 16 + hg * 4 + r) * 32 + lo + 16] = cn;
        }
    }

    // epilogue: fm (channel 0 -> outsum_part) and bm (-> bm_g)
    bf16x8 Ff = *(const bf16x8*)&BFr[l * 8];
    bf16x8 Bb = *(const bf16x8*)&BBr[l * 8];
    float lnfs = ln_fs[lo], lnfb = ln_fb[lo];
    float lnbs = ln_bs[lo], lnbb = ln_bb[lo];
    float bfv = bf_[lo], bwv = bwb[lo];
    f32x4 cif = {bfv, bfv, bfv, bfv};
    f32x4 cib = {bwv, bwv, bwv, bwv};
    float op = 0.f;
    {
        bf16x8 A = *(const bf16x8*)&Hbf[(w * 16 + lo) * 40 + hg * 8];
        f32x4 f = __builtin_amdgcn_mfma_f32_16x16x32_bf16(A, Ff, cif, 0, 0, 0);
        f32x4 g = __builtin_amdgcn_mfma_f32_16x16x32_bf16(A, Bb, cib, 0, 0, 0);
#pragma unroll
        for (int r = 0; r < 4; r++) {
            int gc = q * 64 + w * 16 + hg * 4 + r;
            {
                float x = f[r];
                float mean = sum16(x) * 0.0625f;
                float d = x - mean;
                float rs = rsqrtf(sum16(d * d) * 0.0625f + 1e-6f);
                op += d * rs * lnfs + lnfb;
            }
            {
                float x = g[r];
                float mean = sum16(x) * 0.0625f;
                float d = x - mean;
                float rs = rsqrtf(sum16(d * d) * 0.0625f + 1e-6f);
                bm_g[(((size_t)b * NO1 + no) * MSG + lo) * NI1 + gc] = d * rs * lnbs + lnbb;
            }
        }
    }
    op += __shfl_xor(op, 16);
    op += __shfl_xor(op, 32);
    if (l == 0) red[w] = op;
    __syncthreads();
    if (tid == 0)
        outsum_part[((size_t)b * NO1 + no) * 2 + q] = red[0] + red[1] + red[2] + red[3];

    // bulk coalesced h writeback
    {
        int lc = tid >> 2, part = tid & 3;
        unsigned int* hdst =
            (unsigned int*)h1bf +
            ((size_t)(b * NO1 + no) * 128 + q * 64 + lc) * 16 + part * 4;
        const unsigned int* hl = (const unsigned int*)Hbf;
#pragma unroll
        for (int j = 0; j < 4; j++) hdst[j] = hl[lc * 20 + part * 4 + j];
    }
}

// ---------------------------------------------------------------------------
// k_post: softmax/error only (8 blocks x 64 threads)
// ---------------------------------------------------------------------------
__global__ void k_post(const float* __restrict__ outsum_part,
                       const int* __restrict__ labels,
                       float* __restrict__ dout, float* __restrict__ gradP,
                       float* __restrict__ ohP, int t) {
    int b = blockIdx.x;
    int no = threadIdx.x;
    float v = (outsum_part[((size_t)b * NO1 + no) * 2] +
               outsum_part[((size_t)b * NO1 + no) * 2 + 1]) * (1.f / 128.f);
    float mx = v;
#pragma unroll
    for (int d = 1; d < 64; d <<= 1) mx = fmaxf(mx, __shfl_xor(mx, d));
    float e = __expf(v - mx);
    float sum = e;
#pragma unroll
    for (int d = 1; d < 64; d <<= 1) sum += __shfl_xor(sum, d);
    int lbl = labels[t * BATCH + b];
    float oh = (no == lbl) ? 1.f : 0.f;
    gradP[b * NO1 + no] = e / sum - oh;
    ohP[b * NO1 + no] = oh;
    dout[((size_t)t * BATCH + b) * NO1 + no] = v;
}

// ---------------------------------------------------------------------------

extern "C" void kernel_launch(void* const* d_in, const int* in_sizes, int n_in,
                              void* d_out, int out_size, void* d_ws, size_t ws_size,
                              hipStream_t stream) {
    const float* inp   = (const float*)d_in[0];
    const int*   labels= (const int*)d_in[1];
    const float* Wi    = (const float*)d_in[2];
    const float* Wh    = (const float*)d_in[3];
    const float* b_lstm= (const float*)d_in[4];
    const float* Wf    = (const float*)d_in[5];
    const float* bf_   = (const float*)d_in[6];
    const float* Wb    = (const float*)d_in[7];
    const float* bwb   = (const float*)d_in[8];
    const float* ln_fs = (const float*)d_in[9];
    const float* ln_fb = (const float*)d_in[10];
    const float* ln_bs = (const float*)d_in[11];
    const float* ln_bb = (const float*)d_in[12];
    float* out = (float*)d_out;

    const size_t SZ0 = (size_t)BATCH * NO0 * 256 * 32;  // 8,388,608
    const size_t SZ1 = (size_t)BATCH * NO1 * 128 * 32;  // 2,097,152

    // No zero-init needed: t==0 is handled by in-kernel flags; every buffer
    // is written before it is read within one launch.
    float* c0 = (float*)d_ws;
    float* c1 = c0 + SZ0;
    unsigned short* h0bf = (unsigned short*)(c1 + SZ1);
    unsigned short* h1bf = h0bf + SZ0;
    float* bm_g        = (float*)(h1bf + SZ1);          // 1,048,576 f
    float* nf_part     = bm_g + 1048576;                // 32,768 f
    float* outsum_part = nf_part + 32768;               // 1,024 f
    float* gradP       = outsum_part + 1024;            // 512
    float* ohP         = gradP + 512;                   // 512
    unsigned short* WhBp = (unsigned short*)(ohP + 512);
    unsigned short* WfBp = WhBp + 4096;
    unsigned short* WbBp = WfBp + 512;
    unsigned short* WiFp = WbBp + 512;                  // 4096

    k_prep<<<36, 256, 0, stream>>>(Wh, Wf, Wb, Wi, WhBp, WfBp, WbBp, WiFp);

    for (int t = 0; t < TSTEPS; t++) {
        if (t) k_merge<<<1920, 256, 0, stream>>>((unsigned int*)h0bf, c0,
                                                 (unsigned int*)h1bf, c1);
        k_l0<<<BATCH * NO0 * 2, 256, 0, stream>>>(inp, Wi, WhBp, b_lstm, WfBp, bf_,
                                                  ln_fs, ln_fb, h0bf, c0, bm_g,
                                                  nf_part, t);
        k_l1<<<BATCH * NO1 * 2, 256, 0, stream>>>(Wi, WhBp, b_lstm, WfBp, bf_,
                                                  ln_fs, ln_fb, WbBp, bwb, ln_bs, ln_bb,
                                                  WiFp, h1bf, c1, nf_part, gradP, ohP,
                                                  bm_g, outsum_part, t);
        k_post<<<BATCH, 64, 0, stream>>>(outsum_part, labels, out, gradP, ohP, t);
    }
}

// Round 13
// 296.045 us; speedup vs baseline: 1.8744x; 1.0328x over previous
//
#include <hip/hip_runtime.h>
#include <hip/hip_bf16.h>

#define SLOW 32
#define MSG 16
#define TSTEPS 4
#define BATCH 8
#define NI0 256
#define NO0 128
#define NI1 128
#define NO1 64

typedef __bf16 bf16x8 __attribute__((ext_vector_type(8)));
typedef float f32x4 __attribute__((ext_vector_type(4)));

__device__ __forceinline__ float rcpf(float x) { return __builtin_amdgcn_rcpf(x); }
__device__ __forceinline__ float sigf(float x) { return rcpf(1.f + __expf(-x)); }
__device__ __forceinline__ float tanh_apx(float x) {
    float xc = fminf(fmaxf(x, -15.f), 15.f);
    float e = __expf(-2.f * xc);
    return (1.f - e) * rcpf(1.f + e);
}
__device__ __forceinline__ unsigned short f2bf(float x) {
    __bf16 h = (__bf16)x;
    return __builtin_bit_cast(unsigned short, h);
}
__device__ __forceinline__ float bf2f(unsigned short u) {
    __bf16 h = __builtin_bit_cast(__bf16, u);
    return (float)h;
}
__device__ __forceinline__ float sum16(float v) {
    v += __shfl_xor(v, 1); v += __shfl_xor(v, 2);
    v += __shfl_xor(v, 4); v += __shfl_xor(v, 8);
    return v;
}

// ---------------------------------------------------------------------------
// k_prep: pack B-fragments (bf16) for Wh (8 nt), Wf, Wb, and Wi-fwd (8 nt,
// K zero-padded 16->32). slot (lane l, elem e) = W[k=(l>>4)*8+e][nt*16+(l&15)]
// ---------------------------------------------------------------------------
__global__ void k_prep(const float* __restrict__ Wh, const float* __restrict__ Wf,
                       const float* __restrict__ Wb, const float* __restrict__ Wi,
                       unsigned short* __restrict__ WhBp,
                       unsigned short* __restrict__ WfBp,
                       unsigned short* __restrict__ WbBp,
                       unsigned short* __restrict__ WiFp) {
    int i = blockIdx.x * 256 + threadIdx.x;
    if (i < 4096) {
        int e = i & 7, l = (i >> 3) & 63, nt = i >> 9;
        int k = (l >> 4) * 8 + e, col = nt * 16 + (l & 15);
        WhBp[i] = f2bf(Wh[k * 128 + col]);
    } else if (i < 4608) {
        int j = i - 4096;
        int e = j & 7, l = j >> 3;
        int k = (l >> 4) * 8 + e;
        WfBp[j] = f2bf(Wf[k * 16 + (l & 15)]);
    } else if (i < 5120) {
        int j = i - 4608;
        int e = j & 7, l = j >> 3;
        int k = (l >> 4) * 8 + e;
        WbBp[j] = f2bf(Wb[k * 16 + (l & 15)]);
    } else if (i < 9216) {
        int j = i - 5120;
        int e = j & 7, l = (j >> 3) & 63, nt = j >> 9;
        int k = (l >> 4) * 8 + e, col = nt * 16 + (l & 15);
        WiFp[j] = (k < 16) ? f2bf(Wi[k * 128 + col]) : (unsigned short)0;
    }
}

// ---------------------------------------------------------------------------
// Layer 0: block = (b,no,q), 4 waves, 128 cells, wave w owns 2 m-tiles.
// Barrier-free wave-local recurrence; one staging barrier; t==0 zero states.
// ---------------------------------------------------------------------------
__global__ __launch_bounds__(256) void k_l0(
    const float* __restrict__ inp, const float* __restrict__ Wi,
    const unsigned short* __restrict__ WhBp, const float* __restrict__ b_lstm,
    const unsigned short* __restrict__ WfBp, const float* __restrict__ bf_,
    const float* __restrict__ ln_fs, const float* __restrict__ ln_fb,
    unsigned short* __restrict__ h0bf, float* __restrict__ c0g,
    const float* __restrict__ nb1, float* __restrict__ nf_part, int t) {
    int q = blockIdx.x & 1;
    int no = (blockIdx.x >> 1) & 127;
    int b = blockIdx.x >> 8;
    int tid = threadIdx.x;
    int w = __builtin_amdgcn_readfirstlane(tid >> 6);
    int l = tid & 63, lo = l & 15, hg = l >> 4;

    __shared__ unsigned short Hbf[128 * 40];
    __shared__ unsigned short BW[4096];
    __shared__ unsigned short BFr[512];
    __shared__ float gsh[128];
    __shared__ float mi_l[128];
    __shared__ float wi0[128];
    __shared__ float redn[4][16];

    // ---- staging (single phase) ----
    {
        unsigned int* d = (unsigned int*)BW;
        const unsigned int* s = (const unsigned int*)WhBp;
#pragma unroll
        for (int i = tid; i < 2048; i += 256) d[i] = s[i];
        ((unsigned int*)BFr)[tid] = ((const unsigned int*)WfBp)[tid];
    }
    if (tid < 128) {
        float acc = b_lstm[tid];
        if (t > 0) {
            const float* nbr = nb1 + ((size_t)b * NO0 + no) * MSG;
#pragma unroll
            for (int m = 0; m < MSG; m++) acc += nbr[m] * Wi[(MSG + m) * 128 + tid];
        }
        gsh[tid] = acc;
        wi0[tid] = Wi[tid];
        mi_l[tid] = inp[((size_t)t * BATCH + b) * NI0 + q * 128 + tid];
    }
    {
        int lc = tid >> 1, half = tid & 1;
        unsigned int* hl = (unsigned int*)Hbf;
        if (t > 0) {
            const unsigned int* hsrc =
                (const unsigned int*)h0bf +
                ((size_t)(b * NO0 + no) * 256 + q * 128 + lc) * 16 + half * 8;
#pragma unroll
            for (int j = 0; j < 8; j++) hl[lc * 20 + half * 8 + j] = hsrc[j];
        } else {
#pragma unroll
            for (int j = 0; j < 8; j++) hl[lc * 20 + half * 8 + j] = 0u;
        }
    }
    size_t cbase = (size_t)(b * NO0 + no) * 256 * 32;
    float cst[2][4][2];
    if (t > 0) {
#pragma unroll
        for (int mi_ = 0; mi_ < 2; mi_++)
#pragma unroll
            for (int r = 0; r < 4; r++) {
                int gc = q * 128 + (w * 2 + mi_) * 16 + hg * 4 + r;
#pragma unroll
                for (int hi = 0; hi < 2; hi++)
                    cst[mi_][r][hi] = c0g[cbase + (size_t)gc * 32 + lo + 16 * hi];
            }
    } else {
#pragma unroll
        for (int mi_ = 0; mi_ < 2; mi_++)
#pragma unroll
            for (int r = 0; r < 4; r++) { cst[mi_][r][0] = 0.f; cst[mi_][r][1] = 0.f; }
    }
    __syncthreads();

    float g8[8], w8[8];
#pragma unroll
    for (int nt = 0; nt < 8; nt++) { g8[nt] = gsh[lo + 16 * nt]; w8[nt] = wi0[lo + 16 * nt]; }
    f32x4 miv[2];
#pragma unroll
    for (int mi_ = 0; mi_ < 2; mi_++)
#pragma unroll
        for (int r = 0; r < 4; r++)
            miv[mi_][r] = mi_l[(w * 2 + mi_) * 16 + hg * 4 + r];

#pragma unroll
    for (int micro = 0; micro < 2; micro++) {
#pragma unroll
        for (int mi_ = 0; mi_ < 2; mi_++) {
            int lt = w * 2 + mi_;
            bf16x8 A = *(const bf16x8*)&Hbf[(lt * 16 + lo) * 40 + hg * 8];
            f32x4 acc[4];
#pragma unroll
            for (int g = 0; g < 4; g++) {
                int nt = 2 * g;
                bf16x8 B = *(const bf16x8*)&BW[(nt * 64 + l) * 8];
                f32x4 ci = g8[nt] + miv[mi_] * w8[nt];
                acc[g] = __builtin_amdgcn_mfma_f32_16x16x32_bf16(A, B, ci, 0, 0, 0);
            }
#pragma unroll
            for (int r = 0; r < 4; r++) {
                int lrow = lt * 16 + hg * 4 + r;
                float cn = sigf(acc[1][r]) * cst[mi_][r][0] + sigf(acc[0][r]) * tanh_apx(acc[2][r]);
                cst[mi_][r][0] = cn;
                float hv = sigf(acc[3][r]) * tanh_apx(cn);
                Hbf[lrow * 40 + lo] = f2bf(hv);
                if (micro == 1)
                    c0g[cbase + (size_t)(q * 128 + lrow) * 32 + lo] = cn;
            }
#pragma unroll
            for (int g = 0; g < 4; g++) {
                int nt = 2 * g + 1;
                bf16x8 B = *(const bf16x8*)&BW[(nt * 64 + l) * 8];
                f32x4 ci = g8[nt] + miv[mi_] * w8[nt];
                acc[g] = __builtin_amdgcn_mfma_f32_16x16x32_bf16(A, B, ci, 0, 0, 0);
            }
#pragma unroll
            for (int r = 0; r < 4; r++) {
                int lrow = lt * 16 + hg * 4 + r;
                float cn = sigf(acc[1][r]) * cst[mi_][r][1] + sigf(acc[0][r]) * tanh_apx(acc[2][r]);
                cst[mi_][r][1] = cn;
                float hv = sigf(acc[3][r]) * tanh_apx(cn);
                Hbf[lrow * 40 + lo + 16] = f2bf(hv);
                if (micro == 1)
                    c0g[cbase + (size_t)(q * 128 + lrow) * 32 + lo + 16] = cn;
            }
        }
        // no barrier: recurrence is wave-local
    }

    // epilogue: fm = LN(h @ Wf + bf); raw partial sums
    bf16x8 Ff = *(const bf16x8*)&BFr[l * 8];
    float lnfs = ln_fs[lo], lnfb = ln_fb[lo];
    float bfv = bf_[lo];
    f32x4 cif = {bfv, bfv, bfv, bfv};
    float nfp = 0.f;
#pragma unroll
    for (int mi_ = 0; mi_ < 2; mi_++) {
        int lt = w * 2 + mi_;
        bf16x8 A = *(const bf16x8*)&Hbf[(lt * 16 + lo) * 40 + hg * 8];
        f32x4 f = __builtin_amdgcn_mfma_f32_16x16x32_bf16(A, Ff, cif, 0, 0, 0);
#pragma unroll
        for (int r = 0; r < 4; r++) {
            float x = f[r];
            float mean = sum16(x) * 0.0625f;
            float d = x - mean;
            float rs = rsqrtf(sum16(d * d) * 0.0625f + 1e-6f);
            nfp += d * rs * lnfs + lnfb;
        }
    }
    nfp += __shfl_xor(nfp, 16);
    nfp += __shfl_xor(nfp, 32);
    if (l < 16) redn[w][l] = nfp;
    __syncthreads();
    if (tid < 16)
        nf_part[(((size_t)b * NO0 + no) * 2 + q) * 16 + tid] =
            redn[0][tid] + redn[1][tid] + redn[2][tid] + redn[3][tid];

    // bulk coalesced h writeback
    {
        int lc = tid >> 1, part = tid & 1;
        unsigned int* hdst =
            (unsigned int*)h0bf +
            ((size_t)(b * NO0 + no) * 256 + q * 128 + lc) * 16 + part * 8;
        const unsigned int* hl = (const unsigned int*)Hbf;
#pragma unroll
        for (int j = 0; j < 8; j++) hdst[j] = hl[lc * 20 + part * 8 + j];
    }
}

// ---------------------------------------------------------------------------
// Layer 1: block = (b,no1,q), 4 waves, 64 cells, wave w owns ONE m-tile.
// xf via MFMA from nf_part; t==0 zero states/grad.
// ---------------------------------------------------------------------------
__global__ __launch_bounds__(256) void k_l1(
    const float* __restrict__ Wi, const unsigned short* __restrict__ WhBp,
    const float* __restrict__ b_lstm,
    const unsigned short* __restrict__ WfBp, const float* __restrict__ bf_,
    const float* __restrict__ ln_fs, const float* __restrict__ ln_fb,
    const unsigned short* __restrict__ WbBp, const float* __restrict__ bwb,
    const float* __restrict__ ln_bs, const float* __restrict__ ln_bb,
    const unsigned short* __restrict__ WiFp,
    unsigned short* __restrict__ h1bf, float* __restrict__ c1g,
    const float* __restrict__ nf_part, const float* __restrict__ gradP,
    const float* __restrict__ ohP,
    float* __restrict__ bm_g, float* __restrict__ outsum_part, int t) {
    int q = blockIdx.x & 1;
    int no = (blockIdx.x >> 1) & 63;
    int b = blockIdx.x >> 7;
    int tid = threadIdx.x;
    int w = __builtin_amdgcn_readfirstlane(tid >> 6);
    int l = tid & 63, lo = l & 15, hg = l >> 4;

    __shared__ unsigned short Hbf[64 * 40];
    __shared__ unsigned short BW[4096];
    __shared__ unsigned short WiF[4096];
    __shared__ unsigned short BFr[512];
    __shared__ unsigned short BBr[512];
    __shared__ float gsh[128];
    __shared__ float red[4];

    {
        unsigned int* d = (unsigned int*)BW;
        const unsigned int* s = (const unsigned int*)WhBp;
        unsigned int* d2 = (unsigned int*)WiF;
        const unsigned int* s2 = (const unsigned int*)WiFp;
#pragma unroll
        for (int i = tid; i < 2048; i += 256) { d[i] = s[i]; d2[i] = s2[i]; }
        ((unsigned int*)BFr)[tid] = ((const unsigned int*)WfBp)[tid];
        ((unsigned int*)BBr)[tid] = ((const unsigned int*)WbBp)[tid];
    }
    if (tid < 128) {
        float acc = b_lstm[tid];
        if (t > 0) {
            float g = gradP[b * NO1 + no], oh = ohP[b * NO1 + no];
            acc += g * Wi[MSG * 128 + tid] + oh * Wi[(MSG + 1) * 128 + tid];
        }
        gsh[tid] = acc;
    }
    {
        int lc = tid >> 2, part = tid & 3;
        unsigned int* hl = (unsigned int*)Hbf;
        if (t > 0) {
            const unsigned int* hsrc =
                (const unsigned int*)h1bf +
                ((size_t)(b * NO1 + no) * 128 + q * 64 + lc) * 16 + part * 4;
#pragma unroll
            for (int j = 0; j < 4; j++) hl[lc * 20 + part * 4 + j] = hsrc[j];
        } else {
#pragma unroll
            for (int j = 0; j < 4; j++) hl[lc * 20 + part * 4 + j] = 0u;
        }
    }
    size_t cbase = (size_t)(b * NO1 + no) * 128 * 32;
    float cst[4][2];
    if (t > 0) {
#pragma unroll
        for (int r = 0; r < 4; r++) {
            int gc = q * 64 + w * 16 + hg * 4 + r;
#pragma unroll
            for (int hi = 0; hi < 2; hi++)
                cst[r][hi] = c1g[cbase + (size_t)gc * 32 + lo + 16 * hi];
        }
    } else {
#pragma unroll
        for (int r = 0; r < 4; r++) { cst[r][0] = 0.f; cst[r][1] = 0.f; }
    }
    // A-fragment of nf (bf16): row = cell (w*16+lo), k = m (hg<2), else 0
    bf16x8 Anf;
#pragma unroll
    for (int e = 0; e < 8; e++) Anf[e] = (__bf16)0.f;
    if (hg < 2) {
        const float* p = nf_part +
            ((size_t)b * 128 + q * 64 + w * 16 + lo) * 32 + hg * 8;
#pragma unroll
        for (int e = 0; e < 8; e++)
            Anf[e] = (__bf16)((p[e] + p[e + 16]) * (1.f / 256.f));
    }
    __syncthreads();

    // xf via MFMA
    f32x4 xf4[8];
    {
        f32x4 zz = {0.f, 0.f, 0.f, 0.f};
#pragma unroll
        for (int nt = 0; nt < 8; nt++) {
            bf16x8 B = *(const bf16x8*)&WiF[(nt * 64 + l) * 8];
            xf4[nt] = __builtin_amdgcn_mfma_f32_16x16x32_bf16(Anf, B, zz, 0, 0, 0);
        }
    }
    float g8[8];
#pragma unroll
    for (int nt = 0; nt < 8; nt++) g8[nt] = gsh[lo + 16 * nt];

#pragma unroll
    for (int micro = 0; micro < 2; micro++) {
        bf16x8 A = *(const bf16x8*)&Hbf[(w * 16 + lo) * 40 + hg * 8];
        f32x4 acc[4];
#pragma unroll
        for (int g = 0; g < 4; g++) {
            int nt = 2 * g;
            bf16x8 B = *(const bf16x8*)&BW[(nt * 64 + l) * 8];
            f32x4 ci = xf4[nt] + g8[nt];
            acc[g] = __builtin_amdgcn_mfma_f32_16x16x32_bf16(A, B, ci, 0, 0, 0);
        }
#pragma unroll
        for (int r = 0; r < 4; r++) {
            float cn = sigf(acc[1][r]) * cst[r][0] + sigf(acc[0][r]) * tanh_apx(acc[2][r]);
            cst[r][0] = cn;
            float hv = sigf(acc[3][r]) * tanh_apx(cn);
            Hbf[(w * 16 + hg * 4 + r) * 40 + lo] = f2bf(hv);
            if (micro == 1)
                c1g[cbase + (size_t)(q * 64 + w * 16 + hg * 4 + r) * 32 + lo] = cn;
        }
#pragma unroll
        for (int g = 0; g < 4; g++) {
            int nt = 2 * g + 1;
            bf16x8 B = *(const bf16x8*)&BW[(nt * 64 + l) * 8];
            f32x4 ci = xf4[nt] + g8[nt];
            acc[g] = __builtin_amdgcn_mfma_f32_16x16x32_bf16(A, B, ci, 0, 0, 0);
        }
#pragma unroll
        for (int r = 0; r < 4; r++) {
            float cn = sigf(acc[1][r]) * cst[r][1] + sigf(acc[0][r]) * tanh_apx(acc[2][r]);
            cst[r][1] = cn;
            float hv = sigf(acc[3][r]) * tanh_apx(cn);
            Hbf[(w * 16 + hg * 4 + r) * 40 + lo + 16] = f2bf(hv);
            if (micro == 1)
                c1g[cbase + (size_t)(q * 64 + w * 16 + hg * 4 + r) * 32 + lo + 16] = cn;
        }
    }

    // epilogue: fm (channel 0 -> outsum_part) and bm (-> bm_g)
    bf16x8 Ff = *(const bf16x8*)&BFr[l * 8];
    bf16x8 Bb = *(const bf16x8*)&BBr[l * 8];
    float lnfs = ln_fs[lo], lnfb = ln_fb[lo];
    float lnbs = ln_bs[lo], lnbb = ln_bb[lo];
    float bfv = bf_[lo], bwv = bwb[lo];
    f32x4 cif = {bfv, bfv, bfv, bfv};
    f32x4 cib = {bwv, bwv, bwv, bwv};
    float op = 0.f;
    {
        bf16x8 A = *(const bf16x8*)&Hbf[(w * 16 + lo) * 40 + hg * 8];
        f32x4 f = __builtin_amdgcn_mfma_f32_16x16x32_bf16(A, Ff, cif, 0, 0, 0);
        f32x4 g = __builtin_amdgcn_mfma_f32_16x16x32_bf16(A, Bb, cib, 0, 0, 0);
#pragma unroll
        for (int r = 0; r < 4; r++) {
            int gc = q * 64 + w * 16 + hg * 4 + r;
            {
                float x = f[r];
                float mean = sum16(x) * 0.0625f;
                float d = x - mean;
                float rs = rsqrtf(sum16(d * d) * 0.0625f + 1e-6f);
                op += d * rs * lnfs + lnfb;
            }
            {
                float x = g[r];
                float mean = sum16(x) * 0.0625f;
                float d = x - mean;
                float rs = rsqrtf(sum16(d * d) * 0.0625f + 1e-6f);
                bm_g[(((size_t)b * NO1 + no) * MSG + lo) * NI1 + gc] = d * rs * lnbs + lnbb;
            }
        }
    }
    op += __shfl_xor(op, 16);
    op += __shfl_xor(op, 32);
    if (l == 0) red[w] = op;
    __syncthreads();
    if (tid == 0)
        outsum_part[((size_t)b * NO1 + no) * 2 + q] = red[0] + red[1] + red[2] + red[3];

    // bulk coalesced h writeback
    {
        int lc = tid >> 2, part = tid & 3;
        unsigned int* hdst =
            (unsigned int*)h1bf +
            ((size_t)(b * NO1 + no) * 128 + q * 64 + lc) * 16 + part * 4;
        const unsigned int* hl = (const unsigned int*)Hbf;
#pragma unroll
        for (int j = 0; j < 4; j++) hdst[j] = hl[lc * 20 + part * 4 + j];
    }
}

// ---------------------------------------------------------------------------
// k_step_end: fused between-step work, all parts independent:
//   blocks [0,1920)     : batch-merge of h/c slow channels s<16
//   blocks [1920,1984)  : nb1[b][ni][m] = mean over no1 of bm_g
//   blocks [1984,1992)  : softmax/error
// ---------------------------------------------------------------------------
__global__ __launch_bounds__(256) void k_step_end(
    unsigned int* __restrict__ h0, float* __restrict__ c0,
    unsigned int* __restrict__ h1, float* __restrict__ c1,
    const float* __restrict__ bm_g, float* __restrict__ nb1,
    const float* __restrict__ outsum_part, const int* __restrict__ labels,
    float* __restrict__ dout, float* __restrict__ gradP,
    float* __restrict__ ohP, int t) {
    int bid = blockIdx.x;
    if (bid < 1920) {
        int idx = bid * 256 + threadIdx.x;
        if (idx < 262144) {  // l0 h
            int u = idx & 7, cell = (idx >> 3) & 255, no = idx >> 11;
            size_t base = ((size_t)no * 256 + cell) * 16 + u;
            const size_t strd = (size_t)128 * 256 * 16;
            float s0 = 0.f, s1 = 0.f;
#pragma unroll
            for (int b = 0; b < 8; b++) {
                unsigned int v = h0[base + b * strd];
                s0 += bf2f((unsigned short)(v & 0xffff));
                s1 += bf2f((unsigned short)(v >> 16));
            }
            unsigned int mv = (unsigned int)f2bf(s0 * 0.125f) |
                              ((unsigned int)f2bf(s1 * 0.125f) << 16);
#pragma unroll
            for (int b = 0; b < 8; b++) h0[base + b * strd] = mv;
            return;
        }
        idx -= 262144;
        if (idx < 131072) {  // l0 c
            int s4 = idx & 3, cell = (idx >> 2) & 255, no = idx >> 10;
            float4* C = (float4*)c0;
            size_t base = ((size_t)no * 256 + cell) * 8 + s4;
            const size_t strd = (size_t)128 * 256 * 8;
            float4 a = {0.f, 0.f, 0.f, 0.f};
#pragma unroll
            for (int b = 0; b < 8; b++) {
                float4 v = C[base + b * strd];
                a.x += v.x; a.y += v.y; a.z += v.z; a.w += v.w;
            }
            a.x *= 0.125f; a.y *= 0.125f; a.z *= 0.125f; a.w *= 0.125f;
#pragma unroll
            for (int b = 0; b < 8; b++) C[base + b * strd] = a;
            return;
        }
        idx -= 131072;
        if (idx < 65536) {  // l1 h
            int u = idx & 7, cell = (idx >> 3) & 127, no = idx >> 10;
            size_t base = ((size_t)no * 128 + cell) * 16 + u;
            const size_t strd = (size_t)64 * 128 * 16;
            float s0 = 0.f, s1 = 0.f;
#pragma unroll
            for (int b = 0; b < 8; b++) {
                unsigned int v = h1[base + b * strd];
                s0 += bf2f((unsigned short)(v & 0xffff));
                s1 += bf2f((unsigned short)(v >> 16));
            }
            unsigned int mv = (unsigned int)f2bf(s0 * 0.125f) |
                              ((unsigned int)f2bf(s1 * 0.125f) << 16);
#pragma unroll
            for (int b = 0; b < 8; b++) h1[base + b * strd] = mv;
            return;
        }
        idx -= 65536;
        {  // l1 c (32768)
            int s4 = idx & 3, cell = (idx >> 2) & 127, no = idx >> 9;
            float4* C = (float4*)c1;
            size_t base = ((size_t)no * 128 + cell) * 8 + s4;
            const size_t strd = (size_t)64 * 128 * 8;
            float4 a = {0.f, 0.f, 0.f, 0.f};
#pragma unroll
            for (int b = 0; b < 8; b++) {
                float4 v = C[base + b * strd];
                a.x += v.x; a.y += v.y; a.z += v.z; a.w += v.w;
            }
            a.x *= 0.125f; a.y *= 0.125f; a.z *= 0.125f; a.w *= 0.125f;
#pragma unroll
            for (int b = 0; b < 8; b++) C[base + b * strd] = a;
        }
        return;
    }
    if (bid < 1984) {
        int g = (bid - 1920) * 256 + threadIdx.x;  // < 16384
        int ni = g & 127;
        int m = (g >> 7) & 15;
        int b = g >> 11;
        float a = 0.f;
#pragma unroll 8
        for (int no = 0; no < NO1; no++)
            a += bm_g[(((size_t)b * NO1 + no) * MSG + m) * NI1 + ni];
        nb1[((size_t)b * NI1 + ni) * MSG + m] = a * (1.f / NO1);
        return;
    }
    {
        int b = bid - 1984;
        int no = threadIdx.x;
        if (no < 64) {
            float v = (outsum_part[((size_t)b * NO1 + no) * 2] +
                       outsum_part[((size_t)b * NO1 + no) * 2 + 1]) * (1.f / 128.f);
            float mx = v;
#pragma unroll
            for (int d = 1; d < 64; d <<= 1) mx = fmaxf(mx, __shfl_xor(mx, d));
            float e = __expf(v - mx);
            float sum = e;
#pragma unroll
            for (int d = 1; d < 64; d <<= 1) sum += __shfl_xor(sum, d);
            int lbl = labels[t * BATCH + b];
            float oh = (no == lbl) ? 1.f : 0.f;
            gradP[b * NO1 + no] = e / sum - oh;
            ohP[b * NO1 + no] = oh;
            dout[((size_t)t * BATCH + b) * NO1 + no] = v;
        }
    }
}

// ---------------------------------------------------------------------------

extern "C" void kernel_launch(void* const* d_in, const int* in_sizes, int n_in,
                              void* d_out, int out_size, void* d_ws, size_t ws_size,
                              hipStream_t stream) {
    const float* inp   = (const float*)d_in[0];
    const int*   labels= (const int*)d_in[1];
    const float* Wi    = (const float*)d_in[2];
    const float* Wh    = (const float*)d_in[3];
    const float* b_lstm= (const float*)d_in[4];
    const float* Wf    = (const float*)d_in[5];
    const float* bf_   = (const float*)d_in[6];
    const float* Wb    = (const float*)d_in[7];
    const float* bwb   = (const float*)d_in[8];
    const float* ln_fs = (const float*)d_in[9];
    const float* ln_fb = (const float*)d_in[10];
    const float* ln_bs = (const float*)d_in[11];
    const float* ln_bb = (const float*)d_in[12];
    float* out = (float*)d_out;

    const size_t SZ0 = (size_t)BATCH * NO0 * 256 * 32;  // 8,388,608
    const size_t SZ1 = (size_t)BATCH * NO1 * 128 * 32;  // 2,097,152

    // No memset: t==0 handled by in-kernel flags; all scratch written
    // before read within one launch.
    float* c0 = (float*)d_ws;
    float* c1 = c0 + SZ0;
    unsigned short* h0bf = (unsigned short*)(c1 + SZ1);
    unsigned short* h1bf = h0bf + SZ0;
    float* bm_g        = (float*)(h1bf + SZ1);          // 1,048,576 f
    float* nf_part     = bm_g + 1048576;                // 32,768 f
    float* nb1         = nf_part + 32768;               // 16,384 f
    float* outsum_part = nb1 + 16384;                   // 1,024 f
    float* gradP       = outsum_part + 1024;            // 512
    float* ohP         = gradP + 512;                   // 512
    unsigned short* WhBp = (unsigned short*)(ohP + 512);
    unsigned short* WfBp = WhBp + 4096;
    unsigned short* WbBp = WfBp + 512;
    unsigned short* WiFp = WbBp + 512;                  // 4096

    k_prep<<<36, 256, 0, stream>>>(Wh, Wf, Wb, Wi, WhBp, WfBp, WbBp, WiFp);

    for (int t = 0; t < TSTEPS; t++) {
        k_l0<<<BATCH * NO0 * 2, 256, 0, stream>>>(inp, Wi, WhBp, b_lstm, WfBp, bf_,
                                                  ln_fs, ln_fb, h0bf, c0, nb1,
                                                  nf_part, t);
        k_l1<<<BATCH * NO1 * 2, 256, 0, stream>>>(Wi, WhBp, b_lstm, WfBp, bf_,
                                                  ln_fs, ln_fb, WbBp, bwb, ln_bs, ln_bb,
                                                  WiFp, h1bf, c1, nf_part, gradP, ohP,
                                                  bm_g, outsum_part, t);
        k_step_end<<<1992, 256, 0, stream>>>((unsigned int*)h0bf, c0,
                                             (unsigned int*)h1bf, c1,
                                             bm_g, nb1, outsum_part, labels,
                                             out, gradP, ohP, t);
    }
}